// Round 2
// baseline (934.309 us; speedup 1.0000x reference)
//
#include <hip/hip_runtime.h>
#include <hip/hip_bf16.h>

#define NN 50000
#define NE 800000
#define DD 96
#define HH 32
#define OO 4

// ---------------- scatter: agg[dst] += feat[src], thread per (edge, feature) ----------------

__global__ void k_scatter(const float* __restrict__ feat,
                          const int* __restrict__ edges,
                          float* __restrict__ agg) {
    int idx = blockIdx.x * blockDim.x + threadIdx.x;
    if (idx >= NE * DD) return;
    int e = idx / DD;
    int d = idx - e * DD;
    int s = edges[e];          // src row
    int t = edges[NE + e];     // dst row
    atomicAdd(&agg[t * DD + d], feat[s * DD + d]);
}

// ---------------- layer 1: t1 = relu(((1+eps1)*x + agg) @ W1a + b1a) ----------------

__global__ void k_lin1a(const float* __restrict__ x,
                        const float* __restrict__ agg,
                        const float* __restrict__ W,     // [96,96]
                        const float* __restrict__ b,
                        const float* __restrict__ eps_p,
                        float* __restrict__ out) {
    int idx = blockIdx.x * blockDim.x + threadIdx.x;
    if (idx >= NN * DD) return;
    int i = idx / DD, j = idx - (idx / DD) * DD;
    float eps = 1.0f + eps_p[0];
    const float* xr = x + i * DD;
    const float* ar = agg + i * DD;
    float acc = b[j];
#pragma unroll 8
    for (int k = 0; k < DD; ++k) {
        float z = eps * xr[k] + ar[k];
        acc = fmaf(z, W[k * DD + j], acc);
    }
    out[idx] = fmaxf(acc, 0.0f);
}

// h = relu(t1 @ W1b + b1b)
__global__ void k_lin1b(const float* __restrict__ t1,
                        const float* __restrict__ W,     // [96,96]
                        const float* __restrict__ b,
                        float* __restrict__ out) {
    int idx = blockIdx.x * blockDim.x + threadIdx.x;
    if (idx >= NN * DD) return;
    int i = idx / DD, j = idx - (idx / DD) * DD;
    const float* tr = t1 + i * DD;
    float acc = b[j];
#pragma unroll 8
    for (int k = 0; k < DD; ++k) {
        acc = fmaf(tr[k], W[k * DD + j], acc);
    }
    out[idx] = fmaxf(acc, 0.0f);
}

// ---------------- layer 2: t2 = relu(((1+eps2)*h + agg2) @ W2a + b2a), [N,32] ----------------

__global__ void k_lin2a(const float* __restrict__ h,
                        const float* __restrict__ agg,
                        const float* __restrict__ W,     // [96,32]
                        const float* __restrict__ b,
                        const float* __restrict__ eps_p,
                        float* __restrict__ out) {
    int idx = blockIdx.x * blockDim.x + threadIdx.x;
    if (idx >= NN * HH) return;
    int i = idx / HH, j = idx - (idx / HH) * HH;
    float eps = 1.0f + eps_p[0];
    const float* hr = h + i * DD;
    const float* ar = agg + i * DD;
    float acc = b[j];
#pragma unroll 8
    for (int k = 0; k < DD; ++k) {
        float z = eps * hr[k] + ar[k];
        acc = fmaf(z, W[k * HH + j], acc);
    }
    out[idx] = fmaxf(acc, 0.0f);
}

// h2 = relu(t2 @ W2b + b2b), [N,32]
__global__ void k_lin2b(const float* __restrict__ t2,
                        const float* __restrict__ W,     // [32,32]
                        const float* __restrict__ b,
                        float* __restrict__ out) {
    int idx = blockIdx.x * blockDim.x + threadIdx.x;
    if (idx >= NN * HH) return;
    int i = idx / HH, j = idx - (idx / HH) * HH;
    const float* tr = t2 + i * HH;
    float acc = b[j];
#pragma unroll
    for (int k = 0; k < HH; ++k) {
        acc = fmaf(tr[k], W[k * HH + j], acc);
    }
    out[idx] = fmaxf(acc, 0.0f);
}

// out = h2 @ Wh + bh, [N,4] -> f32
__global__ void k_head(const float* __restrict__ h2,
                       const float* __restrict__ W,      // [32,4]
                       const float* __restrict__ b,
                       float* __restrict__ out) {
    int idx = blockIdx.x * blockDim.x + threadIdx.x;
    if (idx >= NN * OO) return;
    int i = idx / OO, o = idx - (idx / OO) * OO;
    const float* hr = h2 + i * HH;
    float acc = b[o];
#pragma unroll
    for (int k = 0; k < HH; ++k) {
        acc = fmaf(hr[k], W[k * OO + o], acc);
    }
    out[idx] = acc;
}

extern "C" void kernel_launch(void* const* d_in, const int* in_sizes, int n_in,
                              void* d_out, int out_size, void* d_ws, size_t ws_size,
                              hipStream_t stream) {
    const float* x    = (const float*)d_in[0];
    const int*   edges= (const int*)d_in[1];
    const float* eps1 = (const float*)d_in[2];
    const float* eps2 = (const float*)d_in[3];
    const float* W1a  = (const float*)d_in[4];
    const float* b1a  = (const float*)d_in[5];
    const float* W1b  = (const float*)d_in[6];
    const float* b1b  = (const float*)d_in[7];
    const float* W2a  = (const float*)d_in[8];
    const float* b2a  = (const float*)d_in[9];
    const float* W2b  = (const float*)d_in[10];
    const float* b2b  = (const float*)d_in[11];
    const float* Wh   = (const float*)d_in[12];
    const float* bh   = (const float*)d_in[13];

    // workspace layout (fp32): agg | t1 (reused as t2) | h (reused as h2)
    float* agg = (float*)d_ws;                // NN*DD
    float* t1  = agg + NN * DD;               // NN*DD
    float* h   = t1 + NN * DD;                // NN*DD
    float* t2  = t1;                          // NN*HH (t1 dead after lin1b)
    float* h2  = h;                           // NN*HH (h dead after lin2a)

    const int B = 256;

    // layer 1 aggregation
    hipMemsetAsync(agg, 0, (size_t)NN * DD * sizeof(float), stream);
    k_scatter<<<(NE * DD + B - 1) / B, B, 0, stream>>>(x, edges, agg);
    k_lin1a<<<(NN * DD + B - 1) / B, B, 0, stream>>>(x, agg, W1a, b1a, eps1, t1);
    k_lin1b<<<(NN * DD + B - 1) / B, B, 0, stream>>>(t1, W1b, b1b, h);

    // layer 2 aggregation (reuse agg buffer)
    hipMemsetAsync(agg, 0, (size_t)NN * DD * sizeof(float), stream);
    k_scatter<<<(NE * DD + B - 1) / B, B, 0, stream>>>(h, edges, agg);
    k_lin2a<<<(NN * HH + B - 1) / B, B, 0, stream>>>(h, agg, W2a, b2a, eps2, t2);
    k_lin2b<<<(NN * HH + B - 1) / B, B, 0, stream>>>(t2, W2b, b2b, h2);
    k_head<<<(NN * OO + B - 1) / B, B, 0, stream>>>(h2, Wh, bh, (float*)d_out);
}

// Round 3
// 594.239 us; speedup vs baseline: 1.5723x; 1.5723x over previous
//
#include <hip/hip_runtime.h>
#include <hip/hip_bf16.h>

#define NN 50000
#define NE 800000
#define DD 96
#define HH 32
#define OO 4

#define SCAN_B 256
#define NB ((NN + SCAN_B - 1) / SCAN_B)   // 196 scan blocks

// ---------- CSR build ----------

__global__ void k_hist(const int* __restrict__ edges, int* __restrict__ cnt) {
    int e = blockIdx.x * blockDim.x + threadIdx.x;
    if (e >= NE) return;
    atomicAdd(&cnt[edges[NE + e]], 1);
}

// per-block exclusive prescan of cnt -> pre, block totals -> bsum
__global__ void k_scan_block(const int* __restrict__ cnt, int* __restrict__ pre,
                             int* __restrict__ bsum) {
    __shared__ int s[SCAN_B];
    int t = threadIdx.x;
    int i = blockIdx.x * SCAN_B + t;
    int v = (i < NN) ? cnt[i] : 0;
    s[t] = v;
    __syncthreads();
    for (int off = 1; off < SCAN_B; off <<= 1) {
        int a = (t >= off) ? s[t - off] : 0;
        __syncthreads();
        s[t] += a;
        __syncthreads();
    }
    if (i < NN) pre[i] = s[t] - v;             // exclusive within block
    if (t == SCAN_B - 1) bsum[blockIdx.x] = s[t];
}

// single block: exclusive scan of bsum -> boff
__global__ void k_scan_mid(const int* __restrict__ bsum, int* __restrict__ boff) {
    __shared__ int s[SCAN_B];
    int t = threadIdx.x;
    int v = (t < NB) ? bsum[t] : 0;
    s[t] = v;
    __syncthreads();
    for (int off = 1; off < SCAN_B; off <<= 1) {
        int a = (t >= off) ? s[t - off] : 0;
        __syncthreads();
        s[t] += a;
        __syncthreads();
    }
    if (t < NB) boff[t] = s[t] - v;
}

// rowptr[i] = pre[i] + boff[block]; cur[i] = rowptr[i]; rowptr[NN] = NE
__global__ void k_scan_add(int* __restrict__ rowptr, const int* __restrict__ boff,
                           int* __restrict__ cur) {
    int i = blockIdx.x * SCAN_B + threadIdx.x;
    if (i < NN) {
        int v = rowptr[i] + boff[blockIdx.x];
        rowptr[i] = v;
        cur[i] = v;
    }
    if (i == 0) rowptr[NN] = NE;
}

__global__ void k_fill(const int* __restrict__ edges, int* __restrict__ cur,
                       int* __restrict__ csr_src) {
    int e = blockIdx.x * blockDim.x + threadIdx.x;
    if (e >= NE) return;
    int s = edges[e];
    int t = edges[NE + e];
    int pos = atomicAdd(&cur[t], 1);
    csr_src[pos] = s;
}

// ---------- aggregation (gather): z[i][d] = (1+eps)*feat[i][d] + sum_in feat[s][d] ----------

__global__ void k_agg(const float* __restrict__ feat, const int* __restrict__ rowptr,
                      const int* __restrict__ csr_src, const float* __restrict__ eps_p,
                      float* __restrict__ z) {
    int idx = blockIdx.x * blockDim.x + threadIdx.x;
    if (idx >= NN * DD) return;
    int i = idx / DD, d = idx - i * DD;
    int p0 = rowptr[i], p1 = rowptr[i + 1];
    float acc = 0.0f;
    for (int p = p0; p < p1; ++p) {
        int s = csr_src[p];                    // wave-mostly-uniform
        acc += feat[s * DD + d];               // coalesced across d
    }
    z[idx] = fmaf(1.0f + eps_p[0], feat[idx], acc);
}

// ---------- dense: out = act(in @ W + b), ROWS rows per thread ----------

template <int ROWS, int KIN, int KOUT, bool RELU>
__global__ void k_lin(const float* __restrict__ in, const float* __restrict__ W,
                      const float* __restrict__ b, float* __restrict__ out) {
    static_assert(NN % ROWS == 0, "no row tail");
    constexpr int NG = NN / ROWS;
    int g = blockIdx.x * blockDim.x + threadIdx.x;
    if (g >= NG * KOUT) return;
    int j = g % KOUT;
    int ig = g / KOUT;
    const float* ip = in + (size_t)(ig * ROWS) * KIN;
    float bj = b[j];
    float acc[ROWS];
#pragma unroll
    for (int r = 0; r < ROWS; ++r) acc[r] = bj;
#pragma unroll 4
    for (int k = 0; k < KIN; ++k) {
        float w = W[k * KOUT + j];             // coalesced across j, L1-resident
#pragma unroll
        for (int r = 0; r < ROWS; ++r)
            acc[r] = fmaf(ip[r * KIN + k], w, acc[r]);
    }
    float* op = out + (size_t)(ig * ROWS) * KOUT + j;
#pragma unroll
    for (int r = 0; r < ROWS; ++r)
        op[r * KOUT] = RELU ? fmaxf(acc[r], 0.0f) : acc[r];
}

// ---------- launch ----------

extern "C" void kernel_launch(void* const* d_in, const int* in_sizes, int n_in,
                              void* d_out, int out_size, void* d_ws, size_t ws_size,
                              hipStream_t stream) {
    const float* x    = (const float*)d_in[0];
    const int*   edges= (const int*)d_in[1];
    const float* eps1 = (const float*)d_in[2];
    const float* eps2 = (const float*)d_in[3];
    const float* W1a  = (const float*)d_in[4];
    const float* b1a  = (const float*)d_in[5];
    const float* W1b  = (const float*)d_in[6];
    const float* b1b  = (const float*)d_in[7];
    const float* W2a  = (const float*)d_in[8];
    const float* b2a  = (const float*)d_in[9];
    const float* W2b  = (const float*)d_in[10];
    const float* b2b  = (const float*)d_in[11];
    const float* Wh   = (const float*)d_in[12];
    const float* bh   = (const float*)d_in[13];

    // workspace layout (16B-aligned chunks)
    char* w = (char*)d_ws;
    int*   cur     = (int*)w;                 w += ((size_t)NN * 4 + 15) / 16 * 16;        // hist then cursor
    int*   rowptr  = (int*)w;                 w += ((size_t)(NN + 1) * 4 + 15) / 16 * 16;
    int*   bsum    = (int*)w;                 w += 4096;
    int*   boff    = (int*)w;                 w += 4096;
    int*   csr_src = (int*)w;                 w += ((size_t)NE * 4 + 15) / 16 * 16;
    float* z       = (float*)w;               w += (size_t)NN * DD * 4;                    // z1 / z2 / h2
    float* t       = (float*)w;               w += (size_t)NN * DD * 4;                    // t1 / t2
    float* h       = (float*)w;               w += (size_t)NN * DD * 4;                    // h

    const int B = 256;

    // --- CSR build (once, reused by both layers) ---
    hipMemsetAsync(cur, 0, (size_t)NN * 4, stream);
    k_hist<<<(NE + B - 1) / B, B, 0, stream>>>(edges, cur);
    k_scan_block<<<NB, SCAN_B, 0, stream>>>(cur, rowptr, bsum);
    k_scan_mid<<<1, SCAN_B, 0, stream>>>(bsum, boff);
    k_scan_add<<<NB, SCAN_B, 0, stream>>>(rowptr, boff, cur);
    k_fill<<<(NE + B - 1) / B, B, 0, stream>>>(edges, cur, csr_src);

    // --- layer 1 ---
    k_agg<<<(NN * DD + B - 1) / B, B, 0, stream>>>(x, rowptr, csr_src, eps1, z);
    k_lin<4, DD, DD, true><<<((NN / 4) * DD + B - 1) / B, B, 0, stream>>>(z, W1a, b1a, t);
    k_lin<4, DD, DD, true><<<((NN / 4) * DD + B - 1) / B, B, 0, stream>>>(t, W1b, b1b, h);

    // --- layer 2 ---
    k_agg<<<(NN * DD + B - 1) / B, B, 0, stream>>>(h, rowptr, csr_src, eps2, z);
    k_lin<4, DD, HH, true><<<((NN / 4) * HH + B - 1) / B, B, 0, stream>>>(z, W2a, b2a, t);
    k_lin<4, HH, HH, true><<<((NN / 4) * HH + B - 1) / B, B, 0, stream>>>(t, W2b, b2b, z);
    k_lin<4, HH, OO, false><<<((NN / 4) * OO + B - 1) / B, B, 0, stream>>>(z, Wh, bh, (float*)d_out);
}

// Round 4
// 434.437 us; speedup vs baseline: 2.1506x; 1.3678x over previous
//
#include <hip/hip_runtime.h>
#include <hip/hip_bf16.h>

#define NN 50000
#define NE 800000
#define DD 96
#define HH 32
#define OO 4

#define SCAN_B 256
#define NB ((NN + SCAN_B - 1) / SCAN_B)   // 196 scan blocks

// ---------- CSR build ----------

__global__ void k_hist(const int* __restrict__ edges, int* __restrict__ cnt) {
    int e = blockIdx.x * blockDim.x + threadIdx.x;
    if (e >= NE) return;
    atomicAdd(&cnt[edges[NE + e]], 1);
}

__global__ void k_scan_block(const int* __restrict__ cnt, int* __restrict__ pre,
                             int* __restrict__ bsum) {
    __shared__ int s[SCAN_B];
    int t = threadIdx.x;
    int i = blockIdx.x * SCAN_B + t;
    int v = (i < NN) ? cnt[i] : 0;
    s[t] = v;
    __syncthreads();
    for (int off = 1; off < SCAN_B; off <<= 1) {
        int a = (t >= off) ? s[t - off] : 0;
        __syncthreads();
        s[t] += a;
        __syncthreads();
    }
    if (i < NN) pre[i] = s[t] - v;
    if (t == SCAN_B - 1) bsum[blockIdx.x] = s[t];
}

__global__ void k_scan_mid(const int* __restrict__ bsum, int* __restrict__ boff) {
    __shared__ int s[SCAN_B];
    int t = threadIdx.x;
    int v = (t < NB) ? bsum[t] : 0;
    s[t] = v;
    __syncthreads();
    for (int off = 1; off < SCAN_B; off <<= 1) {
        int a = (t >= off) ? s[t - off] : 0;
        __syncthreads();
        s[t] += a;
        __syncthreads();
    }
    if (t < NB) boff[t] = s[t] - v;
}

__global__ void k_scan_add(int* __restrict__ rowptr, const int* __restrict__ boff,
                           int* __restrict__ cur) {
    int i = blockIdx.x * SCAN_B + threadIdx.x;
    if (i < NN) {
        int v = rowptr[i] + boff[blockIdx.x];
        rowptr[i] = v;
        cur[i] = v;
    }
    if (i == 0) rowptr[NN] = NE;
}

__global__ void k_fill(const int* __restrict__ edges, int* __restrict__ cur,
                       int* __restrict__ csr_src) {
    int e = blockIdx.x * blockDim.x + threadIdx.x;
    if (e >= NE) return;
    int s = edges[e];
    int t = edges[NE + e];
    int pos = atomicAdd(&cur[t], 1);
    csr_src[pos] = s;
}

// ---------- fused aggregation (gather, float4, 4-way edge unroll) ----------
// out[i] = relu((1+eps)*y[i] + sum_{s in N(i)} y[s] + b)

__device__ inline void acc4(float4& a, const float4 f) {
    a.x += f.x; a.y += f.y; a.z += f.z; a.w += f.w;
}

template <int DIM>
__global__ void k_agg_fused(const float* __restrict__ y, const int* __restrict__ rowptr,
                            const int* __restrict__ csr_src, const float* __restrict__ eps_p,
                            const float* __restrict__ b, float* __restrict__ out) {
    constexpr int V = DIM / 4;
    int idx = blockIdx.x * blockDim.x + threadIdx.x;
    if (idx >= NN * V) return;
    int i = idx / V, v = idx - (idx / V) * V;
    const float4* y4 = (const float4*)y;
    int p0 = rowptr[i], p1 = rowptr[i + 1];
    float4 a0 = {0,0,0,0}, a1 = {0,0,0,0}, a2 = {0,0,0,0}, a3 = {0,0,0,0};
    int p = p0;
    for (; p + 4 <= p1; p += 4) {
        int s0 = csr_src[p], s1 = csr_src[p+1], s2 = csr_src[p+2], s3 = csr_src[p+3];
        float4 f0 = y4[(size_t)s0 * V + v];
        float4 f1 = y4[(size_t)s1 * V + v];
        float4 f2 = y4[(size_t)s2 * V + v];
        float4 f3 = y4[(size_t)s3 * V + v];
        acc4(a0, f0); acc4(a1, f1); acc4(a2, f2); acc4(a3, f3);
    }
    for (; p < p1; ++p) {
        int s = csr_src[p];
        acc4(a0, y4[(size_t)s * V + v]);
    }
    float4 self = y4[(size_t)i * V + v];
    float4 bb = ((const float4*)b)[v];
    float e = 1.0f + eps_p[0];
    float4 r;
    r.x = fmaxf(fmaf(e, self.x, a0.x + a1.x + a2.x + a3.x) + bb.x, 0.0f);
    r.y = fmaxf(fmaf(e, self.y, a0.y + a1.y + a2.y + a3.y) + bb.y, 0.0f);
    r.z = fmaxf(fmaf(e, self.z, a0.z + a1.z + a2.z + a3.z) + bb.z, 0.0f);
    r.w = fmaxf(fmaf(e, self.w, a0.w + a1.w + a2.w + a3.w) + bb.w, 0.0f);
    ((float4*)out)[idx] = r;
}

// ---------- dense: out = act(in @ W [+ b]), ROWS rows/thread, float4 k-loads ----------

template <int ROWS, int KIN, int KOUT, bool RELU, bool BIAS>
__global__ void k_lin(const float* __restrict__ in, const float* __restrict__ W,
                      const float* __restrict__ b, float* __restrict__ out) {
    static_assert(NN % ROWS == 0 && KIN % 4 == 0, "");
    constexpr int NG = NN / ROWS;
    int g = blockIdx.x * blockDim.x + threadIdx.x;
    if (g >= NG * KOUT) return;
    int j = g % KOUT;
    int ig = g / KOUT;
    const float4* ip4 = (const float4*)(in + (size_t)ig * ROWS * KIN);
    float acc[ROWS];
    float bj = BIAS ? b[j] : 0.0f;
#pragma unroll
    for (int r = 0; r < ROWS; ++r) acc[r] = bj;
    for (int k4 = 0; k4 < KIN / 4; ++k4) {
        float4 xv[ROWS];
#pragma unroll
        for (int r = 0; r < ROWS; ++r) xv[r] = ip4[r * (KIN / 4) + k4];
#pragma unroll
        for (int kk = 0; kk < 4; ++kk) {
            float w = W[(k4 * 4 + kk) * KOUT + j];
            const float* xs = (const float*)xv;
#pragma unroll
            for (int r = 0; r < ROWS; ++r)
                acc[r] = fmaf(xs[r * 4 + kk], w, acc[r]);
        }
    }
    float* op = out + (size_t)ig * ROWS * KOUT + j;
#pragma unroll
    for (int r = 0; r < ROWS; ++r)
        op[r * KOUT] = RELU ? fmaxf(acc[r], 0.0f) : acc[r];
}

// ---------- launch ----------

extern "C" void kernel_launch(void* const* d_in, const int* in_sizes, int n_in,
                              void* d_out, int out_size, void* d_ws, size_t ws_size,
                              hipStream_t stream) {
    const float* x    = (const float*)d_in[0];
    const int*   edges= (const int*)d_in[1];
    const float* eps1 = (const float*)d_in[2];
    const float* eps2 = (const float*)d_in[3];
    const float* W1a  = (const float*)d_in[4];
    const float* b1a  = (const float*)d_in[5];
    const float* W1b  = (const float*)d_in[6];
    const float* b1b  = (const float*)d_in[7];
    const float* W2a  = (const float*)d_in[8];
    const float* b2a  = (const float*)d_in[9];
    const float* W2b  = (const float*)d_in[10];
    const float* b2b  = (const float*)d_in[11];
    const float* Wh   = (const float*)d_in[12];
    const float* bh   = (const float*)d_in[13];

    char* w = (char*)d_ws;
    int*   cur     = (int*)w;   w += ((size_t)NN * 4 + 15) / 16 * 16;
    int*   rowptr  = (int*)w;   w += ((size_t)(NN + 1) * 4 + 15) / 16 * 16;
    int*   bsum    = (int*)w;   w += 4096;
    int*   boff    = (int*)w;   w += 4096;
    int*   csr_src = (int*)w;   w += ((size_t)NE * 4 + 15) / 16 * 16;
    float* bz      = (float*)w; w += (size_t)NN * DD * 4;   // y1 / y2 / h2
    float* bt      = (float*)w; w += (size_t)NN * DD * 4;   // t1 / t2
    float* bh_     = (float*)w; w += (size_t)NN * DD * 4;   // h

    const int B = 256;

    // --- CSR build (once) ---
    hipMemsetAsync(cur, 0, (size_t)NN * 4, stream);
    k_hist<<<(NE + B - 1) / B, B, 0, stream>>>(edges, cur);
    k_scan_block<<<NB, SCAN_B, 0, stream>>>(cur, rowptr, bsum);
    k_scan_mid<<<1, SCAN_B, 0, stream>>>(bsum, boff);
    k_scan_add<<<NB, SCAN_B, 0, stream>>>(rowptr, boff, cur);
    k_fill<<<(NE + B - 1) / B, B, 0, stream>>>(edges, cur, csr_src);

    // --- layer 1 (commuted: y1 = x@W1a, then fused agg+eps+bias+relu) ---
    k_lin<4, DD, DD, false, false><<<((NN / 4) * DD + B - 1) / B, B, 0, stream>>>(x, W1a, nullptr, bz);
    k_agg_fused<DD><<<(NN * (DD / 4) + B - 1) / B, B, 0, stream>>>(bz, rowptr, csr_src, eps1, b1a, bt);
    k_lin<4, DD, DD, true, true><<<((NN / 4) * DD + B - 1) / B, B, 0, stream>>>(bt, W1b, b1b, bh_);

    // --- layer 2 (commuted: y2 = h@W2a [N,32], 3x less gather traffic) ---
    k_lin<4, DD, HH, false, false><<<((NN / 4) * HH + B - 1) / B, B, 0, stream>>>(bh_, W2a, nullptr, bz);
    k_agg_fused<HH><<<(NN * (HH / 4) + B - 1) / B, B, 0, stream>>>(bz, rowptr, csr_src, eps2, b2a, bt);
    k_lin<4, HH, HH, true, true><<<((NN / 4) * HH + B - 1) / B, B, 0, stream>>>(bt, W2b, b2b, bz);
    k_lin<4, HH, OO, false, true><<<((NN / 4) * OO + B - 1) / B, B, 0, stream>>>(bz, Wh, bh, (float*)d_out);
}

// Round 5
// 266.044 us; speedup vs baseline: 3.5119x; 1.6330x over previous
//
#include <hip/hip_runtime.h>
#include <hip/hip_bf16.h>

#define NN 50000
#define NE 800000
#define DD 96
#define HH 32
#define OO 4

#define SCAN_B 256
#define NB ((NN + SCAN_B - 1) / SCAN_B)

typedef unsigned short ushort_t;
typedef unsigned int uint_t;
typedef __attribute__((ext_vector_type(8))) short short8;
typedef __attribute__((ext_vector_type(4))) float f32x4;

__device__ inline ushort_t f2bf(float f) {
    uint_t b = __float_as_uint(f);
    return (ushort_t)((b + 0x7fffu + ((b >> 16) & 1u)) >> 16);   // RNE
}
__device__ inline float bf2f(ushort_t u) {
    return __uint_as_float(((uint_t)u) << 16);
}

// ---------- CSR build ----------

__global__ void k_hist(const int* __restrict__ edges, int* __restrict__ cnt) {
    int e = blockIdx.x * blockDim.x + threadIdx.x;
    if (e >= NE) return;
    atomicAdd(&cnt[edges[NE + e]], 1);
}

__global__ void k_scan_block(const int* __restrict__ cnt, int* __restrict__ pre,
                             int* __restrict__ bsum) {
    __shared__ int s[SCAN_B];
    int t = threadIdx.x;
    int i = blockIdx.x * SCAN_B + t;
    int v = (i < NN) ? cnt[i] : 0;
    s[t] = v;
    __syncthreads();
    for (int off = 1; off < SCAN_B; off <<= 1) {
        int a = (t >= off) ? s[t - off] : 0;
        __syncthreads();
        s[t] += a;
        __syncthreads();
    }
    if (i < NN) pre[i] = s[t] - v;
    if (t == SCAN_B - 1) bsum[blockIdx.x] = s[t];
}

__global__ void k_scan_mid(const int* __restrict__ bsum, int* __restrict__ boff) {
    __shared__ int s[SCAN_B];
    int t = threadIdx.x;
    int v = (t < NB) ? bsum[t] : 0;
    s[t] = v;
    __syncthreads();
    for (int off = 1; off < SCAN_B; off <<= 1) {
        int a = (t >= off) ? s[t - off] : 0;
        __syncthreads();
        s[t] += a;
        __syncthreads();
    }
    if (t < NB) boff[t] = s[t] - v;
}

__global__ void k_scan_add(int* __restrict__ rowptr, const int* __restrict__ boff,
                           int* __restrict__ cur) {
    int i = blockIdx.x * SCAN_B + threadIdx.x;
    if (i < NN) {
        int v = rowptr[i] + boff[blockIdx.x];
        rowptr[i] = v;
        cur[i] = v;
    }
    if (i == 0) rowptr[NN] = NE;
}

__global__ void k_fill(const int* __restrict__ edges, int* __restrict__ cur,
                       int* __restrict__ csr_src) {
    int e = blockIdx.x * blockDim.x + threadIdx.x;
    if (e >= NE) return;
    int s = edges[e];
    int t = edges[NE + e];
    int pos = atomicAdd(&cur[t], 1);
    csr_src[pos] = s;
}

// ---------- fp32 -> bf16 conversion ----------

__global__ void k_cvt(const float* __restrict__ in, ushort_t* __restrict__ out, int n4) {
    int i = blockIdx.x * blockDim.x + threadIdx.x;
    if (i >= n4) return;
    float4 f = ((const float4*)in)[i];
    uint2 o;
    o.x = (uint_t)f2bf(f.x) | ((uint_t)f2bf(f.y) << 16);
    o.y = (uint_t)f2bf(f.z) | ((uint_t)f2bf(f.w) << 16);
    ((uint2*)out)[i] = o;
}

// all three weight matrices in one launch: W1a[96x96] | W1b[96x96] | W2a[96x32]
__global__ void k_cvtW(const float* __restrict__ Wa, const float* __restrict__ Wb,
                       const float* __restrict__ Wc, ushort_t* __restrict__ out) {
    int i = blockIdx.x * blockDim.x + threadIdx.x;
    const int na = DD * DD, nb = DD * DD, nc = DD * HH;
    if (i >= na + nb + nc) return;
    float f;
    if (i < na) f = Wa[i];
    else if (i < na + nb) f = Wb[i - na];
    else f = Wc[i - na - nb];
    out[i] = f2bf(f);
}

// ---------- MFMA GEMM: out_bf16[NN,KOUT] = act(in_bf16[NN,KIN] @ W_bf16[KIN,KOUT] [+b]) ----------
// one 16-row M-tile per wave, all N-tiles + K-chunks in registers

template <int KIN, int KOUT, bool RELU, bool BIAS>
__global__ void k_mfma(const ushort_t* __restrict__ A, const ushort_t* __restrict__ Bw,
                       const float* __restrict__ bias, ushort_t* __restrict__ out) {
    constexpr int KC = KIN / 32;    // K chunks of 32
    constexpr int NT = KOUT / 16;   // N tiles of 16
    constexpr int MT = NN / 16;     // 3125 M tiles
    int lane = threadIdx.x & 63;
    int widx = threadIdx.x >> 6;
    int tile = blockIdx.x * 4 + widx;
    if (tile >= MT) return;
    int row0 = tile * 16;
    int q = lane >> 4;              // quad 0..3
    int l16 = lane & 15;

    // B fragments: B[k][n], n = l16, k = q*8 + j (within chunk)
    short8 bf[NT][KC];
#pragma unroll
    for (int nt = 0; nt < NT; ++nt)
#pragma unroll
        for (int c = 0; c < KC; ++c)
#pragma unroll
            for (int j = 0; j < 8; ++j) {
                int k = c * 32 + q * 8 + j;
                bf[nt][c][j] = (short)Bw[k * KOUT + nt * 16 + l16];
            }

    // A fragments: A[m][k], m = l16, k = q*8 + j  -> one 16B load per chunk
    short8 af[KC];
#pragma unroll
    for (int c = 0; c < KC; ++c) {
        uint4 av = *(const uint4*)(A + (size_t)(row0 + l16) * KIN + c * 32 + q * 8);
        af[c] = *(short8*)&av;
    }

    f32x4 acc[NT];
#pragma unroll
    for (int nt = 0; nt < NT; ++nt) acc[nt] = (f32x4){0.f, 0.f, 0.f, 0.f};
#pragma unroll
    for (int nt = 0; nt < NT; ++nt)
#pragma unroll
        for (int c = 0; c < KC; ++c)
            acc[nt] = __builtin_amdgcn_mfma_f32_16x16x32_bf16(af[c], bf[nt][c], acc[nt], 0, 0, 0);

    // epilogue: C/D layout col=l16, row=q*4+r
#pragma unroll
    for (int nt = 0; nt < NT; ++nt) {
        int col = nt * 16 + l16;
        float bv = BIAS ? bias[col] : 0.0f;
#pragma unroll
        for (int r = 0; r < 4; ++r) {
            int row = q * 4 + r;
            float v = acc[nt][r] + bv;
            if (RELU) v = fmaxf(v, 0.0f);
            out[(size_t)(row0 + row) * KOUT + col] = f2bf(v);
        }
    }
}

// ---------- fused aggregation on bf16: out = relu((1+eps)*y[i] + sum_in y[s] + b) ----------

__device__ inline void addbf8(float* a, uint4 u) {
    a[0] += __uint_as_float(u.x << 16);
    a[1] += __uint_as_float(u.x & 0xffff0000u);
    a[2] += __uint_as_float(u.y << 16);
    a[3] += __uint_as_float(u.y & 0xffff0000u);
    a[4] += __uint_as_float(u.z << 16);
    a[5] += __uint_as_float(u.z & 0xffff0000u);
    a[6] += __uint_as_float(u.w << 16);
    a[7] += __uint_as_float(u.w & 0xffff0000u);
}

template <int DIM>
__global__ void k_aggb(const ushort_t* __restrict__ y, const int* __restrict__ rowptr,
                       const int* __restrict__ csr_src, const float* __restrict__ eps_p,
                       const float* __restrict__ b, ushort_t* __restrict__ out) {
    constexpr int V = DIM / 8;     // 16B groups per row
    int idx = blockIdx.x * blockDim.x + threadIdx.x;
    if (idx >= NN * V) return;
    int i = idx / V, v = idx - i * V;
    const uint4* y4 = (const uint4*)y;
    int p0 = rowptr[i], p1 = rowptr[i + 1];
    float a0[8] = {0,0,0,0,0,0,0,0}, a1[8] = {0,0,0,0,0,0,0,0};
    float a2[8] = {0,0,0,0,0,0,0,0}, a3[8] = {0,0,0,0,0,0,0,0};
    int p = p0;
    for (; p + 4 <= p1; p += 4) {
        int s0 = csr_src[p], s1 = csr_src[p+1], s2 = csr_src[p+2], s3 = csr_src[p+3];
        uint4 f0 = y4[(size_t)s0 * V + v];
        uint4 f1 = y4[(size_t)s1 * V + v];
        uint4 f2 = y4[(size_t)s2 * V + v];
        uint4 f3 = y4[(size_t)s3 * V + v];
        addbf8(a0, f0); addbf8(a1, f1); addbf8(a2, f2); addbf8(a3, f3);
    }
    for (; p < p1; ++p) addbf8(a0, y4[(size_t)csr_src[p] * V + v]);

    // self + bias
    uint4 su = y4[(size_t)i * V + v];
    float s8[8];
    s8[0] = __uint_as_float(su.x << 16); s8[1] = __uint_as_float(su.x & 0xffff0000u);
    s8[2] = __uint_as_float(su.y << 16); s8[3] = __uint_as_float(su.y & 0xffff0000u);
    s8[4] = __uint_as_float(su.z << 16); s8[5] = __uint_as_float(su.z & 0xffff0000u);
    s8[6] = __uint_as_float(su.w << 16); s8[7] = __uint_as_float(su.w & 0xffff0000u);
    float4 bl = ((const float4*)b)[2 * v];
    float4 bh = ((const float4*)b)[2 * v + 1];
    float bb[8] = {bl.x, bl.y, bl.z, bl.w, bh.x, bh.y, bh.z, bh.w};
    float e = 1.0f + eps_p[0];
    ushort_t r[8];
#pragma unroll
    for (int k = 0; k < 8; ++k) {
        float vv = fmaf(e, s8[k], a0[k] + a1[k] + a2[k] + a3[k]) + bb[k];
        r[k] = f2bf(fmaxf(vv, 0.0f));
    }
    uint4 o;
    o.x = (uint_t)r[0] | ((uint_t)r[1] << 16);
    o.y = (uint_t)r[2] | ((uint_t)r[3] << 16);
    o.z = (uint_t)r[4] | ((uint_t)r[5] << 16);
    o.w = (uint_t)r[6] | ((uint_t)r[7] << 16);
    ((uint4*)out)[idx] = o;
}

// ---------- small dense (bf16 in, fp32 out): out = act(in @ W + b) ----------

template <int ROWS, int KIN, int KOUT, bool RELU, bool BIAS>
__global__ void k_lin_bf(const ushort_t* __restrict__ in, const float* __restrict__ W,
                         const float* __restrict__ b, float* __restrict__ out) {
    constexpr int NG = NN / ROWS;
    int g = blockIdx.x * blockDim.x + threadIdx.x;
    if (g >= NG * KOUT) return;
    int j = g % KOUT;
    int ig = g / KOUT;
    const ushort_t* ip = in + (size_t)ig * ROWS * KIN;
    float acc[ROWS];
    float bj = BIAS ? b[j] : 0.0f;
#pragma unroll
    for (int r = 0; r < ROWS; ++r) acc[r] = bj;
#pragma unroll 4
    for (int k = 0; k < KIN; ++k) {
        float w = W[k * KOUT + j];
#pragma unroll
        for (int r = 0; r < ROWS; ++r)
            acc[r] = fmaf(bf2f(ip[r * KIN + k]), w, acc[r]);
    }
    float* op = out + (size_t)ig * ROWS * KOUT + j;
#pragma unroll
    for (int r = 0; r < ROWS; ++r)
        op[r * KOUT] = RELU ? fmaxf(acc[r], 0.0f) : acc[r];
}

// fp32 dense (head)
template <int ROWS, int KIN, int KOUT, bool RELU, bool BIAS>
__global__ void k_lin(const float* __restrict__ in, const float* __restrict__ W,
                      const float* __restrict__ b, float* __restrict__ out) {
    constexpr int NG = NN / ROWS;
    int g = blockIdx.x * blockDim.x + threadIdx.x;
    if (g >= NG * KOUT) return;
    int j = g % KOUT;
    int ig = g / KOUT;
    const float* ip = in + (size_t)ig * ROWS * KIN;
    float acc[ROWS];
    float bj = BIAS ? b[j] : 0.0f;
#pragma unroll
    for (int r = 0; r < ROWS; ++r) acc[r] = bj;
#pragma unroll 4
    for (int k = 0; k < KIN; ++k) {
        float w = W[k * KOUT + j];
#pragma unroll
        for (int r = 0; r < ROWS; ++r)
            acc[r] = fmaf(ip[r * KIN + k], w, acc[r]);
    }
    float* op = out + (size_t)ig * ROWS * KOUT + j;
#pragma unroll
    for (int r = 0; r < ROWS; ++r)
        op[r * KOUT] = RELU ? fmaxf(acc[r], 0.0f) : acc[r];
}

// ---------- launch ----------

extern "C" void kernel_launch(void* const* d_in, const int* in_sizes, int n_in,
                              void* d_out, int out_size, void* d_ws, size_t ws_size,
                              hipStream_t stream) {
    const float* x    = (const float*)d_in[0];
    const int*   edges= (const int*)d_in[1];
    const float* eps1 = (const float*)d_in[2];
    const float* eps2 = (const float*)d_in[3];
    const float* W1a  = (const float*)d_in[4];
    const float* b1a  = (const float*)d_in[5];
    const float* W1b  = (const float*)d_in[6];
    const float* b1b  = (const float*)d_in[7];
    const float* W2a  = (const float*)d_in[8];
    const float* b2a  = (const float*)d_in[9];
    const float* W2b  = (const float*)d_in[10];
    const float* b2b  = (const float*)d_in[11];
    const float* Wh   = (const float*)d_in[12];
    const float* bh   = (const float*)d_in[13];

    auto al = [](size_t n) { return (n + 255) / 256 * 256; };
    char* w = (char*)d_ws;
    int*      cur     = (int*)w;       w += al((size_t)NN * 4);
    int*      rowptr  = (int*)w;       w += al((size_t)(NN + 1) * 4);
    int*      bsum    = (int*)w;       w += 4096;
    int*      boff    = (int*)w;       w += 4096;
    int*      csr_src = (int*)w;       w += al((size_t)NE * 4);
    ushort_t* wbf     = (ushort_t*)w;  w += al((size_t)(DD*DD + DD*DD + DD*HH) * 2);
    ushort_t* x_bf    = (ushort_t*)w;  w += al((size_t)NN * DD * 2);
    ushort_t* y1_bf   = (ushort_t*)w;  w += al((size_t)NN * DD * 2);
    ushort_t* t1_bf   = (ushort_t*)w;  w += al((size_t)NN * DD * 2);
    ushort_t* h_bf    = (ushort_t*)w;  w += al((size_t)NN * DD * 2);
    ushort_t* y2_bf   = (ushort_t*)w;  w += al((size_t)NN * HH * 2);
    ushort_t* t2_bf   = (ushort_t*)w;  w += al((size_t)NN * HH * 2);
    float*    h2      = (float*)w;     w += al((size_t)NN * HH * 4);

    ushort_t* W1a_bf = wbf;
    ushort_t* W1b_bf = wbf + DD * DD;
    ushort_t* W2a_bf = wbf + 2 * DD * DD;

    const int B = 256;
    const int MFMA_GRID = (NN / 16 + 3) / 4;   // 4 M-tiles (waves) per block

    // --- CSR build ---
    hipMemsetAsync(cur, 0, (size_t)NN * 4, stream);
    k_hist<<<(NE + B - 1) / B, B, 0, stream>>>(edges, cur);
    k_scan_block<<<NB, SCAN_B, 0, stream>>>(cur, rowptr, bsum);
    k_scan_mid<<<1, SCAN_B, 0, stream>>>(bsum, boff);
    k_scan_add<<<NB, SCAN_B, 0, stream>>>(rowptr, boff, cur);
    k_fill<<<(NE + B - 1) / B, B, 0, stream>>>(edges, cur, csr_src);

    // --- conversions ---
    k_cvt<<<(NN * DD / 4 + B - 1) / B, B, 0, stream>>>(x, x_bf, NN * DD / 4);
    k_cvtW<<<(DD*DD*2 + DD*HH + B - 1) / B, B, 0, stream>>>(W1a, W1b, W2a, wbf);

    // --- layer 1 (commuted): y1 = x@W1a; t1 = relu((1+e)y1+agg(y1)+b1a); h = relu(t1@W1b+b1b) ---
    k_mfma<DD, DD, false, false><<<MFMA_GRID, B, 0, stream>>>(x_bf, W1a_bf, nullptr, y1_bf);
    k_aggb<DD><<<(NN * (DD/8) + B - 1) / B, B, 0, stream>>>(y1_bf, rowptr, csr_src, eps1, b1a, t1_bf);
    k_mfma<DD, DD, true, true><<<MFMA_GRID, B, 0, stream>>>(t1_bf, W1b_bf, b1b, h_bf);

    // --- layer 2 (commuted): y2 = h@W2a [N,32]; t2 = relu(...); h2 = relu(t2@W2b+b2b); out = h2@Wh+bh ---
    k_mfma<DD, HH, false, false><<<MFMA_GRID, B, 0, stream>>>(h_bf, W2a_bf, nullptr, y2_bf);
    k_aggb<HH><<<(NN * (HH/8) + B - 1) / B, B, 0, stream>>>(y2_bf, rowptr, csr_src, eps2, b2a, t2_bf);
    k_lin_bf<4, HH, HH, true, true><<<((NN/4) * HH + B - 1) / B, B, 0, stream>>>(t2_bf, W2b, b2b, h2);
    k_lin<4, HH, OO, false, true><<<((NN/4) * OO + B - 1) / B, B, 0, stream>>>(h2, Wh, bh, (float*)d_out);
}

// Round 6
// 265.715 us; speedup vs baseline: 3.5162x; 1.0012x over previous
//
#include <hip/hip_runtime.h>

#define NN 50000
#define NE 800000
#define DD 96
#define HH 32
#define OO 4

#define SCAN_B 256
#define NB ((NN + SCAN_B - 1) / SCAN_B)

typedef unsigned short ushort_t;
typedef unsigned int uint_t;
typedef __attribute__((ext_vector_type(8))) short short8;
typedef __attribute__((ext_vector_type(4))) float f32x4;

__device__ inline ushort_t f2bf(float f) {
    uint_t b = __float_as_uint(f);
    return (ushort_t)((b + 0x7fffu + ((b >> 16) & 1u)) >> 16);   // RNE
}
__device__ inline float bf2f(ushort_t u) {
    return __uint_as_float(((uint_t)u) << 16);
}

// ---------- merged prep: cvt(x)->bf16 | W->MFMA-fragment bf16 | degree histogram ----------
// W frag layout per matrix (KIN=96, KC=3): frag[(nt*KC+c)*64 + lane] is short8 with
// element j = W[c*32 + (lane>>4)*8 + j][nt*16 + (lane&15)]

#define PREP_CVT_B  ((NN * DD / 4 + 255) / 256)     // 4688
#define PREP_W_B    11                               // 2688 frag-threads
#define PREP_HIST_B ((NE / 4 + 255) / 256)           // 782

__global__ void k_prep(const float* __restrict__ x, ushort_t* __restrict__ x_bf,
                       const float* __restrict__ W1a, const float* __restrict__ W1b,
                       const float* __restrict__ W2a, ushort_t* __restrict__ wf,
                       const int* __restrict__ edges, int* __restrict__ cnt) {
    int b = blockIdx.x;
    if (b < PREP_CVT_B) {
        int i = b * 256 + threadIdx.x;
        if (i < NN * DD / 4) {
            float4 f = ((const float4*)x)[i];
            uint2 o;
            o.x = (uint_t)f2bf(f.x) | ((uint_t)f2bf(f.y) << 16);
            o.y = (uint_t)f2bf(f.z) | ((uint_t)f2bf(f.w) << 16);
            ((uint2*)x_bf)[i] = o;
        }
        return;
    }
    b -= PREP_CVT_B;
    if (b < PREP_W_B) {
        int tw = b * 256 + threadIdx.x;
        if (tw < 2688) {
            const float* Wsrc; ushort_t* dst; int KOUT, fl;
            if (tw < 1152)      { Wsrc = W1a; dst = wf;         KOUT = DD; fl = tw; }
            else if (tw < 2304) { Wsrc = W1b; dst = wf + 9216;  KOUT = DD; fl = tw - 1152; }
            else                { Wsrc = W2a; dst = wf + 18432; KOUT = HH; fl = tw - 2304; }
            int lane = fl & 63;
            int fc = fl >> 6;            // nt*3 + c
            int c = fc % 3, nt = fc / 3;
            int kb = c * 32 + (lane >> 4) * 8;
            int col = nt * 16 + (lane & 15);
            ushort_t v[8];
#pragma unroll
            for (int j = 0; j < 8; ++j)
                v[j] = f2bf(Wsrc[(size_t)(kb + j) * KOUT + col]);
            *(uint4*)(dst + (size_t)fl * 8) = *(uint4*)v;
        }
        return;
    }
    b -= PREP_W_B;
    int e4 = b * 256 + threadIdx.x;
    if (e4 < NE / 4) {
        int4 tt = ((const int4*)(edges + NE))[e4];
        atomicAdd(&cnt[tt.x], 1);
        atomicAdd(&cnt[tt.y], 1);
        atomicAdd(&cnt[tt.z], 1);
        atomicAdd(&cnt[tt.w], 1);
    }
}

// ---------- scan (rowptr) ----------

__global__ void k_scan_block(const int* __restrict__ cnt, int* __restrict__ pre,
                             int* __restrict__ bsum) {
    __shared__ int s[SCAN_B];
    int t = threadIdx.x;
    int i = blockIdx.x * SCAN_B + t;
    int v = (i < NN) ? cnt[i] : 0;
    s[t] = v;
    __syncthreads();
    for (int off = 1; off < SCAN_B; off <<= 1) {
        int a = (t >= off) ? s[t - off] : 0;
        __syncthreads();
        s[t] += a;
        __syncthreads();
    }
    if (i < NN) pre[i] = s[t] - v;
    if (t == SCAN_B - 1) bsum[blockIdx.x] = s[t];
}

__global__ void k_scan_mid(const int* __restrict__ bsum, int* __restrict__ boff) {
    __shared__ int s[SCAN_B];
    int t = threadIdx.x;
    int v = (t < NB) ? bsum[t] : 0;
    s[t] = v;
    __syncthreads();
    for (int off = 1; off < SCAN_B; off <<= 1) {
        int a = (t >= off) ? s[t - off] : 0;
        __syncthreads();
        s[t] += a;
        __syncthreads();
    }
    if (t < NB) boff[t] = s[t] - v;
}

__global__ void k_scan_add(int* __restrict__ rowptr, const int* __restrict__ boff,
                           int* __restrict__ cur) {
    int i = blockIdx.x * SCAN_B + threadIdx.x;
    if (i < NN) {
        int v = rowptr[i] + boff[blockIdx.x];
        rowptr[i] = v;
        cur[i] = v;
    }
    if (i == 0) rowptr[NN] = NE;
}

// ---------- CSR fill: 4 edges/thread, ushort entries ----------

__global__ void k_fill(const int* __restrict__ edges, int* __restrict__ cur,
                       ushort_t* __restrict__ csr) {
    int t4 = blockIdx.x * blockDim.x + threadIdx.x;
    if (t4 >= NE / 4) return;
    int4 ss = ((const int4*)edges)[t4];
    int4 tt = ((const int4*)(edges + NE))[t4];
    int p0 = atomicAdd(&cur[tt.x], 1);
    int p1 = atomicAdd(&cur[tt.y], 1);
    int p2 = atomicAdd(&cur[tt.z], 1);
    int p3 = atomicAdd(&cur[tt.w], 1);
    csr[p0] = (ushort_t)ss.x;
    csr[p1] = (ushort_t)ss.y;
    csr[p2] = (ushort_t)ss.z;
    csr[p3] = (ushort_t)ss.w;
}

// ---------- MFMA GEMM (B pre-swizzled to fragments) ----------

template <int KIN, int KOUT, bool RELU, bool BIAS>
__global__ void k_mfma(const ushort_t* __restrict__ A, const ushort_t* __restrict__ Bf,
                       const float* __restrict__ bias, ushort_t* __restrict__ out) {
    constexpr int KC = KIN / 32;
    constexpr int NT = KOUT / 16;
    constexpr int MT = NN / 16;
    int lane = threadIdx.x & 63;
    int widx = threadIdx.x >> 6;
    int tile = blockIdx.x * 4 + widx;
    if (tile >= MT) return;
    int row0 = tile * 16;
    int q = lane >> 4;
    int l16 = lane & 15;

    const short8* bfp = (const short8*)Bf;
    short8 bf[NT][KC];
#pragma unroll
    for (int nt = 0; nt < NT; ++nt)
#pragma unroll
        for (int c = 0; c < KC; ++c)
            bf[nt][c] = bfp[(nt * KC + c) * 64 + lane];

    short8 af[KC];
#pragma unroll
    for (int c = 0; c < KC; ++c) {
        uint4 av = *(const uint4*)(A + (size_t)(row0 + l16) * KIN + c * 32 + q * 8);
        af[c] = *(short8*)&av;
    }

    f32x4 acc[NT];
#pragma unroll
    for (int nt = 0; nt < NT; ++nt) acc[nt] = (f32x4){0.f, 0.f, 0.f, 0.f};
#pragma unroll
    for (int nt = 0; nt < NT; ++nt)
#pragma unroll
        for (int c = 0; c < KC; ++c)
            acc[nt] = __builtin_amdgcn_mfma_f32_16x16x32_bf16(af[c], bf[nt][c], acc[nt], 0, 0, 0);

#pragma unroll
    for (int nt = 0; nt < NT; ++nt) {
        int col = nt * 16 + l16;
        float bv = BIAS ? bias[col] : 0.0f;
#pragma unroll
        for (int r = 0; r < 4; ++r) {
            int row = q * 4 + r;
            float v = acc[nt][r] + bv;
            if (RELU) v = fmaxf(v, 0.0f);
            out[(size_t)(row0 + row) * KOUT + col] = f2bf(v);
        }
    }
}

// ---------- fused aggregation on bf16 (8-way edge unroll, ushort csr) ----------

__device__ inline void addbf8(float* a, uint4 u) {
    a[0] += __uint_as_float(u.x << 16);
    a[1] += __uint_as_float(u.x & 0xffff0000u);
    a[2] += __uint_as_float(u.y << 16);
    a[3] += __uint_as_float(u.y & 0xffff0000u);
    a[4] += __uint_as_float(u.z << 16);
    a[5] += __uint_as_float(u.z & 0xffff0000u);
    a[6] += __uint_as_float(u.w << 16);
    a[7] += __uint_as_float(u.w & 0xffff0000u);
}

template <int DIM>
__global__ void k_aggb(const ushort_t* __restrict__ y, const int* __restrict__ rowptr,
                       const ushort_t* __restrict__ csr, const float* __restrict__ eps_p,
                       const float* __restrict__ b, ushort_t* __restrict__ out) {
    constexpr int V = DIM / 8;
    int idx = blockIdx.x * blockDim.x + threadIdx.x;
    if (idx >= NN * V) return;
    int i = idx / V, v = idx - i * V;
    const uint4* y4 = (const uint4*)y;
    int p0 = rowptr[i], p1 = rowptr[i + 1];
    float a0[8] = {0,0,0,0,0,0,0,0}, a1[8] = {0,0,0,0,0,0,0,0};
    float a2[8] = {0,0,0,0,0,0,0,0}, a3[8] = {0,0,0,0,0,0,0,0};
    int p = p0;
    for (; p + 8 <= p1; p += 8) {
        int s0 = csr[p],   s1 = csr[p+1], s2 = csr[p+2], s3 = csr[p+3];
        int s4 = csr[p+4], s5 = csr[p+5], s6 = csr[p+6], s7 = csr[p+7];
        uint4 f0 = y4[(size_t)s0 * V + v];
        uint4 f1 = y4[(size_t)s1 * V + v];
        uint4 f2 = y4[(size_t)s2 * V + v];
        uint4 f3 = y4[(size_t)s3 * V + v];
        uint4 f4 = y4[(size_t)s4 * V + v];
        uint4 f5 = y4[(size_t)s5 * V + v];
        uint4 f6 = y4[(size_t)s6 * V + v];
        uint4 f7 = y4[(size_t)s7 * V + v];
        addbf8(a0, f0); addbf8(a1, f1); addbf8(a2, f2); addbf8(a3, f3);
        addbf8(a0, f4); addbf8(a1, f5); addbf8(a2, f6); addbf8(a3, f7);
    }
    for (; p + 4 <= p1; p += 4) {
        int s0 = csr[p], s1 = csr[p+1], s2 = csr[p+2], s3 = csr[p+3];
        uint4 f0 = y4[(size_t)s0 * V + v];
        uint4 f1 = y4[(size_t)s1 * V + v];
        uint4 f2 = y4[(size_t)s2 * V + v];
        uint4 f3 = y4[(size_t)s3 * V + v];
        addbf8(a0, f0); addbf8(a1, f1); addbf8(a2, f2); addbf8(a3, f3);
    }
    for (; p < p1; ++p) addbf8(a0, y4[(size_t)csr[p] * V + v]);

    uint4 su = y4[(size_t)i * V + v];
    float s8[8];
    s8[0] = __uint_as_float(su.x << 16); s8[1] = __uint_as_float(su.x & 0xffff0000u);
    s8[2] = __uint_as_float(su.y << 16); s8[3] = __uint_as_float(su.y & 0xffff0000u);
    s8[4] = __uint_as_float(su.z << 16); s8[5] = __uint_as_float(su.z & 0xffff0000u);
    s8[6] = __uint_as_float(su.w << 16); s8[7] = __uint_as_float(su.w & 0xffff0000u);
    float4 bl = ((const float4*)b)[2 * v];
    float4 bhv = ((const float4*)b)[2 * v + 1];
    float bb[8] = {bl.x, bl.y, bl.z, bl.w, bhv.x, bhv.y, bhv.z, bhv.w};
    float e = 1.0f + eps_p[0];
    ushort_t r[8];
#pragma unroll
    for (int k = 0; k < 8; ++k) {
        float vv = fmaf(e, s8[k], a0[k] + a1[k] + a2[k] + a3[k]) + bb[k];
        r[k] = f2bf(fmaxf(vv, 0.0f));
    }
    uint4 o;
    o.x = (uint_t)r[0] | ((uint_t)r[1] << 16);
    o.y = (uint_t)r[2] | ((uint_t)r[3] << 16);
    o.z = (uint_t)r[4] | ((uint_t)r[5] << 16);
    o.w = (uint_t)r[6] | ((uint_t)r[7] << 16);
    ((uint4*)out)[idx] = o;
}

// ---------- fused tail: out = (relu(t2 @ W2b + b2b)) @ Wh + bh, one node/thread ----------

__global__ void k_tail(const ushort_t* __restrict__ t2, const float* __restrict__ W2b,
                       const float* __restrict__ b2b, const float* __restrict__ Wh,
                       const float* __restrict__ bhp, float* __restrict__ out) {
    int i = blockIdx.x * blockDim.x + threadIdx.x;
    if (i >= NN) return;
    float tin[HH];
    const uint4* tp = (const uint4*)(t2 + (size_t)i * HH);
#pragma unroll
    for (int g = 0; g < HH / 8; ++g) {
        uint4 u = tp[g];
        tin[g*8+0] = __uint_as_float(u.x << 16); tin[g*8+1] = __uint_as_float(u.x & 0xffff0000u);
        tin[g*8+2] = __uint_as_float(u.y << 16); tin[g*8+3] = __uint_as_float(u.y & 0xffff0000u);
        tin[g*8+4] = __uint_as_float(u.z << 16); tin[g*8+5] = __uint_as_float(u.z & 0xffff0000u);
        tin[g*8+6] = __uint_as_float(u.w << 16); tin[g*8+7] = __uint_as_float(u.w & 0xffff0000u);
    }
    float o[OO];
#pragma unroll
    for (int oo = 0; oo < OO; ++oo) o[oo] = bhp[oo];
    for (int j = 0; j < HH; ++j) {
        float acc = b2b[j];
#pragma unroll 8
        for (int k = 0; k < HH; ++k)
            acc = fmaf(tin[k], W2b[k * HH + j], acc);
        acc = fmaxf(acc, 0.0f);
#pragma unroll
        for (int oo = 0; oo < OO; ++oo)
            o[oo] = fmaf(acc, Wh[j * OO + oo], o[oo]);
    }
    float4 ov = {o[0], o[1], o[2], o[3]};
    ((float4*)out)[i] = ov;
}

// ---------- launch ----------

extern "C" void kernel_launch(void* const* d_in, const int* in_sizes, int n_in,
                              void* d_out, int out_size, void* d_ws, size_t ws_size,
                              hipStream_t stream) {
    const float* x    = (const float*)d_in[0];
    const int*   edges= (const int*)d_in[1];
    const float* eps1 = (const float*)d_in[2];
    const float* eps2 = (const float*)d_in[3];
    const float* W1a  = (const float*)d_in[4];
    const float* b1a  = (const float*)d_in[5];
    const float* W1b  = (const float*)d_in[6];
    const float* b1b  = (const float*)d_in[7];
    const float* W2a  = (const float*)d_in[8];
    const float* b2a  = (const float*)d_in[9];
    const float* W2b  = (const float*)d_in[10];
    const float* b2b  = (const float*)d_in[11];
    const float* Wh   = (const float*)d_in[12];
    const float* bh   = (const float*)d_in[13];

    auto al = [](size_t n) { return (n + 255) / 256 * 256; };
    char* w = (char*)d_ws;
    int*      cur     = (int*)w;       w += al((size_t)NN * 4);
    int*      rowptr  = (int*)w;       w += al((size_t)(NN + 1) * 4);
    int*      bsum    = (int*)w;       w += 4096;
    int*      boff    = (int*)w;       w += 4096;
    ushort_t* csr     = (ushort_t*)w;  w += al((size_t)NE * 2);
    ushort_t* wf      = (ushort_t*)w;  w += al((size_t)21504 * 2);
    ushort_t* x_bf    = (ushort_t*)w;  w += al((size_t)NN * DD * 2);
    ushort_t* y1_bf   = (ushort_t*)w;  w += al((size_t)NN * DD * 2);
    ushort_t* t1_bf   = (ushort_t*)w;  w += al((size_t)NN * DD * 2);
    ushort_t* h_bf    = (ushort_t*)w;  w += al((size_t)NN * DD * 2);
    ushort_t* y2_bf   = (ushort_t*)w;  w += al((size_t)NN * HH * 2);
    ushort_t* t2_bf   = (ushort_t*)w;  w += al((size_t)NN * HH * 2);

    ushort_t* W1a_f = wf;
    ushort_t* W1b_f = wf + 9216;
    ushort_t* W2a_f = wf + 18432;

    const int B = 256;
    const int MFMA_GRID = (NN / 16 + 3) / 4;

    hipMemsetAsync(cur, 0, (size_t)NN * 4, stream);
    k_prep<<<PREP_CVT_B + PREP_W_B + PREP_HIST_B, B, 0, stream>>>(
        x, x_bf, W1a, W1b, W2a, wf, edges, cur);
    k_scan_block<<<NB, SCAN_B, 0, stream>>>(cur, rowptr, bsum);
    k_scan_mid<<<1, SCAN_B, 0, stream>>>(bsum, boff);
    k_scan_add<<<NB, SCAN_B, 0, stream>>>(rowptr, boff, cur);
    k_fill<<<(NE / 4 + B - 1) / B, B, 0, stream>>>(edges, cur, csr);

    // layer 1 (commuted)
    k_mfma<DD, DD, false, false><<<MFMA_GRID, B, 0, stream>>>(x_bf, W1a_f, nullptr, y1_bf);
    k_aggb<DD><<<(NN * (DD/8) + B - 1) / B, B, 0, stream>>>(y1_bf, rowptr, csr, eps1, b1a, t1_bf);
    k_mfma<DD, DD, true, true><<<MFMA_GRID, B, 0, stream>>>(t1_bf, W1b_f, b1b, h_bf);

    // layer 2 (commuted)
    k_mfma<DD, HH, false, false><<<MFMA_GRID, B, 0, stream>>>(h_bf, W2a_f, nullptr, y2_bf);
    k_aggb<HH><<<(NN * (HH/8) + B - 1) / B, B, 0, stream>>>(y2_bf, rowptr, csr, eps2, b2a, t2_bf);
    k_tail<<<(NN + B - 1) / B, B, 0, stream>>>(t2_bf, W2b, b2b, Wh, bh, (float*)d_out);
}

// Round 7
// 222.330 us; speedup vs baseline: 4.2024x; 1.1951x over previous
//
#include <hip/hip_runtime.h>

#define NN 50000
#define NE 800000
#define DD 96
#define HH 32
#define OO 4
#define ELLW 64   // ELL row stride (max supported degree); Poisson(16) tail @64 ~ 0

typedef unsigned short ushort_t;
typedef unsigned int uint_t;
typedef __attribute__((ext_vector_type(8))) short short8;
typedef __attribute__((ext_vector_type(4))) float f32x4;

__device__ inline ushort_t f2bf(float f) {
    uint_t b = __float_as_uint(f);
    return (ushort_t)((b + 0x7fffu + ((b >> 16) & 1u)) >> 16);   // RNE
}

// ---------- build: W->MFMA fragments | ELL fill (pos via atomic on cur) ----------
// W frag layout (KIN=96, KC=3): frag[(nt*KC+c)*64 + lane] = short8, elem j =
// W[c*32 + (lane>>4)*8 + j][nt*16 + (lane&15)]

#define BUILD_W_B   11                       // 2688 frag-threads
#define BUILD_E_B   ((NE / 4 + 255) / 256)   // 782 blocks, 4 edges/thread

__global__ void k_build(const float* __restrict__ W1a, const float* __restrict__ W1b,
                        const float* __restrict__ W2a, ushort_t* __restrict__ wf,
                        const int* __restrict__ edges, int* __restrict__ cur,
                        ushort_t* __restrict__ ell) {
    int b = blockIdx.x;
    if (b < BUILD_W_B) {
        int tw = b * 256 + threadIdx.x;
        if (tw < 2688) {
            const float* Wsrc; ushort_t* dst; int KOUT, fl;
            if (tw < 1152)      { Wsrc = W1a; dst = wf;         KOUT = DD; fl = tw; }
            else if (tw < 2304) { Wsrc = W1b; dst = wf + 9216;  KOUT = DD; fl = tw - 1152; }
            else                { Wsrc = W2a; dst = wf + 18432; KOUT = HH; fl = tw - 2304; }
            int lane = fl & 63;
            int fc = fl >> 6;
            int c = fc % 3, nt = fc / 3;
            int kb = c * 32 + (lane >> 4) * 8;
            int col = nt * 16 + (lane & 15);
            ushort_t v[8];
#pragma unroll
            for (int j = 0; j < 8; ++j)
                v[j] = f2bf(Wsrc[(size_t)(kb + j) * KOUT + col]);
            *(uint4*)(dst + (size_t)fl * 8) = *(uint4*)v;
        }
        return;
    }
    b -= BUILD_W_B;
    int t4 = b * 256 + threadIdx.x;
    if (t4 >= NE / 4) return;
    int4 ss = ((const int4*)edges)[t4];
    int4 tt = ((const int4*)(edges + NE))[t4];
    int p0 = atomicAdd(&cur[tt.x], 1);
    int p1 = atomicAdd(&cur[tt.y], 1);
    int p2 = atomicAdd(&cur[tt.z], 1);
    int p3 = atomicAdd(&cur[tt.w], 1);
    if (p0 < ELLW) ell[(size_t)tt.x * ELLW + p0] = (ushort_t)ss.x;
    if (p1 < ELLW) ell[(size_t)tt.y * ELLW + p1] = (ushort_t)ss.y;
    if (p2 < ELLW) ell[(size_t)tt.z * ELLW + p2] = (ushort_t)ss.z;
    if (p3 < ELLW) ell[(size_t)tt.w * ELLW + p3] = (ushort_t)ss.w;
}

// ---------- MFMA GEMM (B pre-swizzled); A either bf16 or fp32 (inline cvt) ----------

template <int KIN, int KOUT, bool RELU, bool BIAS, bool A32>
__global__ void k_mfma(const void* __restrict__ Ap, const ushort_t* __restrict__ Bf,
                       const float* __restrict__ bias, ushort_t* __restrict__ out) {
    constexpr int KC = KIN / 32;
    constexpr int NT = KOUT / 16;
    constexpr int MT = NN / 16;
    int lane = threadIdx.x & 63;
    int widx = threadIdx.x >> 6;
    int tile = blockIdx.x * 4 + widx;
    if (tile >= MT) return;
    int row0 = tile * 16;
    int q = lane >> 4;
    int l16 = lane & 15;

    const short8* bfp = (const short8*)Bf;
    short8 bf[NT][KC];
#pragma unroll
    for (int nt = 0; nt < NT; ++nt)
#pragma unroll
        for (int c = 0; c < KC; ++c)
            bf[nt][c] = bfp[(nt * KC + c) * 64 + lane];

    short8 af[KC];
#pragma unroll
    for (int c = 0; c < KC; ++c) {
        if (A32) {
            const float* ap = (const float*)Ap + (size_t)(row0 + l16) * KIN + c * 32 + q * 8;
            float4 f0 = *(const float4*)ap;
            float4 f1 = *(const float4*)(ap + 4);
            ushort_t v[8] = {f2bf(f0.x), f2bf(f0.y), f2bf(f0.z), f2bf(f0.w),
                             f2bf(f1.x), f2bf(f1.y), f2bf(f1.z), f2bf(f1.w)};
            af[c] = *(short8*)v;
        } else {
            uint4 av = *(const uint4*)((const ushort_t*)Ap + (size_t)(row0 + l16) * KIN + c * 32 + q * 8);
            af[c] = *(short8*)&av;
        }
    }

    f32x4 acc[NT];
#pragma unroll
    for (int nt = 0; nt < NT; ++nt) acc[nt] = (f32x4){0.f, 0.f, 0.f, 0.f};
#pragma unroll
    for (int nt = 0; nt < NT; ++nt)
#pragma unroll
        for (int c = 0; c < KC; ++c)
            acc[nt] = __builtin_amdgcn_mfma_f32_16x16x32_bf16(af[c], bf[nt][c], acc[nt], 0, 0, 0);

#pragma unroll
    for (int nt = 0; nt < NT; ++nt) {
        int col = nt * 16 + l16;
        float bv = BIAS ? bias[col] : 0.0f;
#pragma unroll
        for (int r = 0; r < 4; ++r) {
            int row = q * 4 + r;
            float v = acc[nt][r] + bv;
            if (RELU) v = fmaxf(v, 0.0f);
            out[(size_t)(row0 + row) * KOUT + col] = f2bf(v);
        }
    }
}

// ---------- fused aggregation on bf16 over ELL: out = relu((1+e)y[i] + sum y[s] + b) ----------

__device__ inline void addbf8(float* a, uint4 u) {
    a[0] += __uint_as_float(u.x << 16);
    a[1] += __uint_as_float(u.x & 0xffff0000u);
    a[2] += __uint_as_float(u.y << 16);
    a[3] += __uint_as_float(u.y & 0xffff0000u);
    a[4] += __uint_as_float(u.z << 16);
    a[5] += __uint_as_float(u.z & 0xffff0000u);
    a[6] += __uint_as_float(u.w << 16);
    a[7] += __uint_as_float(u.w & 0xffff0000u);
}

template <int DIM>
__global__ void k_aggb(const ushort_t* __restrict__ y, const int* __restrict__ deg,
                       const ushort_t* __restrict__ ell, const float* __restrict__ eps_p,
                       const float* __restrict__ b, ushort_t* __restrict__ out) {
    constexpr int V = DIM / 8;
    int idx = blockIdx.x * blockDim.x + threadIdx.x;
    if (idx >= NN * V) return;
    int i = idx / V, v = idx - i * V;
    const uint4* y4 = (const uint4*)y;
    const ushort_t* er = ell + (size_t)i * ELLW;
    int d = min(deg[i], ELLW);
    float a0[8] = {0,0,0,0,0,0,0,0}, a1[8] = {0,0,0,0,0,0,0,0};
    float a2[8] = {0,0,0,0,0,0,0,0}, a3[8] = {0,0,0,0,0,0,0,0};
    int p = 0;
    for (; p + 8 <= d; p += 8) {
        int s0 = er[p],   s1 = er[p+1], s2 = er[p+2], s3 = er[p+3];
        int s4 = er[p+4], s5 = er[p+5], s6 = er[p+6], s7 = er[p+7];
        uint4 f0 = y4[(size_t)s0 * V + v];
        uint4 f1 = y4[(size_t)s1 * V + v];
        uint4 f2 = y4[(size_t)s2 * V + v];
        uint4 f3 = y4[(size_t)s3 * V + v];
        uint4 f4 = y4[(size_t)s4 * V + v];
        uint4 f5 = y4[(size_t)s5 * V + v];
        uint4 f6 = y4[(size_t)s6 * V + v];
        uint4 f7 = y4[(size_t)s7 * V + v];
        addbf8(a0, f0); addbf8(a1, f1); addbf8(a2, f2); addbf8(a3, f3);
        addbf8(a0, f4); addbf8(a1, f5); addbf8(a2, f6); addbf8(a3, f7);
    }
    for (; p + 4 <= d; p += 4) {
        int s0 = er[p], s1 = er[p+1], s2 = er[p+2], s3 = er[p+3];
        uint4 f0 = y4[(size_t)s0 * V + v];
        uint4 f1 = y4[(size_t)s1 * V + v];
        uint4 f2 = y4[(size_t)s2 * V + v];
        uint4 f3 = y4[(size_t)s3 * V + v];
        addbf8(a0, f0); addbf8(a1, f1); addbf8(a2, f2); addbf8(a3, f3);
    }
    for (; p < d; ++p) addbf8(a0, y4[(size_t)er[p] * V + v]);

    uint4 su = y4[(size_t)i * V + v];
    float s8[8];
    s8[0] = __uint_as_float(su.x << 16); s8[1] = __uint_as_float(su.x & 0xffff0000u);
    s8[2] = __uint_as_float(su.y << 16); s8[3] = __uint_as_float(su.y & 0xffff0000u);
    s8[4] = __uint_as_float(su.z << 16); s8[5] = __uint_as_float(su.z & 0xffff0000u);
    s8[6] = __uint_as_float(su.w << 16); s8[7] = __uint_as_float(su.w & 0xffff0000u);
    float4 bl = ((const float4*)b)[2 * v];
    float4 bhv = ((const float4*)b)[2 * v + 1];
    float bb[8] = {bl.x, bl.y, bl.z, bl.w, bhv.x, bhv.y, bhv.z, bhv.w};
    float e = 1.0f + eps_p[0];
    ushort_t r[8];
#pragma unroll
    for (int k = 0; k < 8; ++k) {
        float vv = fmaf(e, s8[k], a0[k] + a1[k] + a2[k] + a3[k]) + bb[k];
        r[k] = f2bf(fmaxf(vv, 0.0f));
    }
    uint4 o;
    o.x = (uint_t)r[0] | ((uint_t)r[1] << 16);
    o.y = (uint_t)r[2] | ((uint_t)r[3] << 16);
    o.z = (uint_t)r[4] | ((uint_t)r[5] << 16);
    o.w = (uint_t)r[6] | ((uint_t)r[7] << 16);
    ((uint4*)out)[idx] = o;
}

// ---------- fused tail: out = (relu(t2 @ W2b + b2b)) @ Wh + bh ----------

__global__ void k_tail(const ushort_t* __restrict__ t2, const float* __restrict__ W2b,
                       const float* __restrict__ b2b, const float* __restrict__ Wh,
                       const float* __restrict__ bhp, float* __restrict__ out) {
    int i = blockIdx.x * blockDim.x + threadIdx.x;
    if (i >= NN) return;
    float tin[HH];
    const uint4* tp = (const uint4*)(t2 + (size_t)i * HH);
#pragma unroll
    for (int g = 0; g < HH / 8; ++g) {
        uint4 u = tp[g];
        tin[g*8+0] = __uint_as_float(u.x << 16); tin[g*8+1] = __uint_as_float(u.x & 0xffff0000u);
        tin[g*8+2] = __uint_as_float(u.y << 16); tin[g*8+3] = __uint_as_float(u.y & 0xffff0000u);
        tin[g*8+4] = __uint_as_float(u.z << 16); tin[g*8+5] = __uint_as_float(u.z & 0xffff0000u);
        tin[g*8+6] = __uint_as_float(u.w << 16); tin[g*8+7] = __uint_as_float(u.w & 0xffff0000u);
    }
    float o[OO];
#pragma unroll
    for (int oo = 0; oo < OO; ++oo) o[oo] = bhp[oo];
    for (int j = 0; j < HH; ++j) {
        float acc = b2b[j];
#pragma unroll 8
        for (int k = 0; k < HH; ++k)
            acc = fmaf(tin[k], W2b[k * HH + j], acc);
        acc = fmaxf(acc, 0.0f);
#pragma unroll
        for (int oo = 0; oo < OO; ++oo)
            o[oo] = fmaf(acc, Wh[j * OO + oo], o[oo]);
    }
    float4 ov = {o[0], o[1], o[2], o[3]};
    ((float4*)out)[i] = ov;
}

// ---------- launch ----------

extern "C" void kernel_launch(void* const* d_in, const int* in_sizes, int n_in,
                              void* d_out, int out_size, void* d_ws, size_t ws_size,
                              hipStream_t stream) {
    const float* x    = (const float*)d_in[0];
    const int*   edges= (const int*)d_in[1];
    const float* eps1 = (const float*)d_in[2];
    const float* eps2 = (const float*)d_in[3];
    const float* W1a  = (const float*)d_in[4];
    const float* b1a  = (const float*)d_in[5];
    const float* W1b  = (const float*)d_in[6];
    const float* b1b  = (const float*)d_in[7];
    const float* W2a  = (const float*)d_in[8];
    const float* b2a  = (const float*)d_in[9];
    const float* W2b  = (const float*)d_in[10];
    const float* b2b  = (const float*)d_in[11];
    const float* Wh   = (const float*)d_in[12];
    const float* bh   = (const float*)d_in[13];

    auto al = [](size_t n) { return (n + 255) / 256 * 256; };
    char* w = (char*)d_ws;
    int*      cur   = (int*)w;       w += al((size_t)NN * 4);          // degree after build
    ushort_t* ell   = (ushort_t*)w;  w += al((size_t)NN * ELLW * 2);   // 6.4 MB
    ushort_t* wf    = (ushort_t*)w;  w += al((size_t)21504 * 2);
    ushort_t* y1_bf = (ushort_t*)w;  w += al((size_t)NN * DD * 2);
    ushort_t* t1_bf = (ushort_t*)w;  w += al((size_t)NN * DD * 2);
    ushort_t* h_bf  = (ushort_t*)w;  w += al((size_t)NN * DD * 2);
    ushort_t* y2_bf = (ushort_t*)w;  w += al((size_t)NN * HH * 2);
    ushort_t* t2_bf = (ushort_t*)w;  w += al((size_t)NN * HH * 2);

    ushort_t* W1a_f = wf;
    ushort_t* W1b_f = wf + 9216;
    ushort_t* W2a_f = wf + 18432;

    const int B = 256;
    const int MFMA_GRID = (NN / 16 + 3) / 4;

    hipMemsetAsync(cur, 0, (size_t)NN * 4, stream);
    k_build<<<BUILD_W_B + BUILD_E_B, B, 0, stream>>>(W1a, W1b, W2a, wf, edges, cur, ell);

    // layer 1 (commuted): y1 = x@W1a (fp32 A inline-cvt); t1 = relu((1+e)y1+agg(y1)+b1a); h = relu(t1@W1b+b1b)
    k_mfma<DD, DD, false, false, true><<<MFMA_GRID, B, 0, stream>>>(x, W1a_f, nullptr, y1_bf);
    k_aggb<DD><<<(NN * (DD/8) + B - 1) / B, B, 0, stream>>>(y1_bf, cur, ell, eps1, b1a, t1_bf);
    k_mfma<DD, DD, true, true, false><<<MFMA_GRID, B, 0, stream>>>(t1_bf, W1b_f, b1b, h_bf);

    // layer 2 (commuted): y2 = h@W2a [N,32]; t2 = relu((1+e)y2+agg(y2)+b2a); out = tail(t2)
    k_mfma<DD, HH, false, false, false><<<MFMA_GRID, B, 0, stream>>>(h_bf, W2a_f, nullptr, y2_bf);
    k_aggb<HH><<<(NN * (HH/8) + B - 1) / B, B, 0, stream>>>(y2_bf, cur, ell, eps2, b2a, t2_bf);
    k_tail<<<(NN + B - 1) / B, B, 0, stream>>>(t2_bf, W2b, b2b, Wh, bh, (float*)d_out);
}

// Round 8
// 221.739 us; speedup vs baseline: 4.2136x; 1.0027x over previous
//
#include <hip/hip_runtime.h>

#define NN 50000
#define NE 800000
#define DD 96
#define HH 32
#define OO 4
#define ELLW 64   // max degree; deg ~ Poisson(16), P(>64) ~ 0 (guarded anyway)

typedef unsigned short ushort_t;
typedef unsigned int uint_t;
typedef __attribute__((ext_vector_type(8))) short short8;
typedef __attribute__((ext_vector_type(4))) float f32x4;

__device__ inline ushort_t f2bf(float f) {
    uint_t b = __float_as_uint(f);
    return (ushort_t)((b + 0x7fffu + ((b >> 16) & 1u)) >> 16);   // RNE
}

__device__ inline void addbf8(float* a, uint4 u) {
    a[0] += __uint_as_float(u.x << 16);
    a[1] += __uint_as_float(u.x & 0xffff0000u);
    a[2] += __uint_as_float(u.y << 16);
    a[3] += __uint_as_float(u.y & 0xffff0000u);
    a[4] += __uint_as_float(u.z << 16);
    a[5] += __uint_as_float(u.z & 0xffff0000u);
    a[6] += __uint_as_float(u.w << 16);
    a[7] += __uint_as_float(u.w & 0xffff0000u);
}

// ================= k_big1: ELL build | W1b/W2a frag swizzle | y1 = x @ W1a =================
// sections (by blockIdx): [0, EDGE_B) edges, [EDGE_B, EDGE_B+WF_B) W-frags, rest mfma1.

#define EDGE_B ((NE / 4 + 255) / 256)        // 782
#define WF_B   6                              // 1152 (W1b) + 384 (W2a) frag-threads
#define MT1    (NN / 16)                      // 3125 M tiles
#define MFMA1_B ((MT1 + 3) / 4)               // 782

__global__ void k_big1(const int* __restrict__ edges, int* __restrict__ cur,
                       ushort_t* __restrict__ ell,
                       const float* __restrict__ W1b, const float* __restrict__ W2a,
                       ushort_t* __restrict__ wf,
                       const float* __restrict__ x, const float* __restrict__ W1a,
                       ushort_t* __restrict__ y1) {
    int b = blockIdx.x;
    if (b < EDGE_B) {
        int t4 = b * 256 + threadIdx.x;
        if (t4 >= NE / 4) return;
        int4 ss = ((const int4*)edges)[t4];
        int4 tt = ((const int4*)(edges + NE))[t4];
        int p0 = atomicAdd(&cur[tt.x], 1);
        int p1 = atomicAdd(&cur[tt.y], 1);
        int p2 = atomicAdd(&cur[tt.z], 1);
        int p3 = atomicAdd(&cur[tt.w], 1);
        if (p0 < ELLW) ell[(size_t)tt.x * ELLW + p0] = (ushort_t)ss.x;
        if (p1 < ELLW) ell[(size_t)tt.y * ELLW + p1] = (ushort_t)ss.y;
        if (p2 < ELLW) ell[(size_t)tt.z * ELLW + p2] = (ushort_t)ss.z;
        if (p3 < ELLW) ell[(size_t)tt.w * ELLW + p3] = (ushort_t)ss.w;
        return;
    }
    b -= EDGE_B;
    if (b < WF_B) {
        int tw = b * 256 + threadIdx.x;
        if (tw < 1152 + 384) {
            const float* Wsrc; ushort_t* dst; int KOUT, fl;
            if (tw < 1152) { Wsrc = W1b; dst = wf;        KOUT = DD; fl = tw; }
            else           { Wsrc = W2a; dst = wf + 9216; KOUT = HH; fl = tw - 1152; }
            int lane = fl & 63;
            int fc = fl >> 6;            // nt*3 + c
            int c = fc % 3, nt = fc / 3;
            int kb = c * 32 + (lane >> 4) * 8;
            int col = nt * 16 + (lane & 15);
            ushort_t v[8];
#pragma unroll
            for (int j = 0; j < 8; ++j)
                v[j] = f2bf(Wsrc[(size_t)(kb + j) * KOUT + col]);
            *(uint4*)(dst + (size_t)fl * 8) = *(uint4*)v;
        }
        return;
    }
    b -= WF_B;
    // ---- mfma1: y1 = x @ W1a, raw fp32 A and B ----
    constexpr int KC = 3, NT = 6;
    int lane = threadIdx.x & 63;
    int widx = threadIdx.x >> 6;
    int tile = b * 4 + widx;
    if (tile >= MT1) return;
    int row0 = tile * 16;
    int q = lane >> 4;
    int l16 = lane & 15;

    short8 bf[NT][KC];
#pragma unroll
    for (int nt = 0; nt < NT; ++nt)
#pragma unroll
        for (int c = 0; c < KC; ++c) {
            ushort_t v[8];
#pragma unroll
            for (int j = 0; j < 8; ++j)
                v[j] = f2bf(W1a[(size_t)(c * 32 + q * 8 + j) * DD + nt * 16 + l16]);
            bf[nt][c] = *(short8*)v;
        }

    short8 af[KC];
#pragma unroll
    for (int c = 0; c < KC; ++c) {
        const float* ap = x + (size_t)(row0 + l16) * DD + c * 32 + q * 8;
        float4 f0 = *(const float4*)ap;
        float4 f1 = *(const float4*)(ap + 4);
        ushort_t v[8] = {f2bf(f0.x), f2bf(f0.y), f2bf(f0.z), f2bf(f0.w),
                         f2bf(f1.x), f2bf(f1.y), f2bf(f1.z), f2bf(f1.w)};
        af[c] = *(short8*)v;
    }

    f32x4 acc[NT];
#pragma unroll
    for (int nt = 0; nt < NT; ++nt) acc[nt] = (f32x4){0.f, 0.f, 0.f, 0.f};
#pragma unroll
    for (int nt = 0; nt < NT; ++nt)
#pragma unroll
        for (int c = 0; c < KC; ++c)
            acc[nt] = __builtin_amdgcn_mfma_f32_16x16x32_bf16(af[c], bf[nt][c], acc[nt], 0, 0, 0);

#pragma unroll
    for (int nt = 0; nt < NT; ++nt) {
        int col = nt * 16 + l16;
#pragma unroll
        for (int r = 0; r < 4; ++r)
            y1[(size_t)(row0 + q * 4 + r) * DD + col] = f2bf(acc[nt][r]);
    }
}

// ================= aggregation over ELL (bf16): t1 = relu((1+e)y[i] + sum y[s] + b) =========

template <int DIM>
__global__ void k_aggb(const ushort_t* __restrict__ y, const int* __restrict__ deg,
                       const ushort_t* __restrict__ ell, const float* __restrict__ eps_p,
                       const float* __restrict__ b, ushort_t* __restrict__ out) {
    constexpr int V = DIM / 8;
    int idx = blockIdx.x * blockDim.x + threadIdx.x;
    if (idx >= NN * V) return;
    int i = idx / V, v = idx - i * V;
    const uint4* y4 = (const uint4*)y;
    const ushort_t* er = ell + (size_t)i * ELLW;
    int d = min(deg[i], ELLW);
    float a0[8] = {0,0,0,0,0,0,0,0}, a1[8] = {0,0,0,0,0,0,0,0};
    float a2[8] = {0,0,0,0,0,0,0,0}, a3[8] = {0,0,0,0,0,0,0,0};
    int p = 0;
    for (; p + 8 <= d; p += 8) {
        int s0 = er[p],   s1 = er[p+1], s2 = er[p+2], s3 = er[p+3];
        int s4 = er[p+4], s5 = er[p+5], s6 = er[p+6], s7 = er[p+7];
        uint4 f0 = y4[(size_t)s0 * V + v];
        uint4 f1 = y4[(size_t)s1 * V + v];
        uint4 f2 = y4[(size_t)s2 * V + v];
        uint4 f3 = y4[(size_t)s3 * V + v];
        uint4 f4 = y4[(size_t)s4 * V + v];
        uint4 f5 = y4[(size_t)s5 * V + v];
        uint4 f6 = y4[(size_t)s6 * V + v];
        uint4 f7 = y4[(size_t)s7 * V + v];
        addbf8(a0, f0); addbf8(a1, f1); addbf8(a2, f2); addbf8(a3, f3);
        addbf8(a0, f4); addbf8(a1, f5); addbf8(a2, f6); addbf8(a3, f7);
    }
    for (; p + 4 <= d; p += 4) {
        int s0 = er[p], s1 = er[p+1], s2 = er[p+2], s3 = er[p+3];
        uint4 f0 = y4[(size_t)s0 * V + v];
        uint4 f1 = y4[(size_t)s1 * V + v];
        uint4 f2 = y4[(size_t)s2 * V + v];
        uint4 f3 = y4[(size_t)s3 * V + v];
        addbf8(a0, f0); addbf8(a1, f1); addbf8(a2, f2); addbf8(a3, f3);
    }
    for (; p < d; ++p) addbf8(a0, y4[(size_t)er[p] * V + v]);

    uint4 su = y4[(size_t)i * V + v];
    float s8[8];
    s8[0] = __uint_as_float(su.x << 16); s8[1] = __uint_as_float(su.x & 0xffff0000u);
    s8[2] = __uint_as_float(su.y << 16); s8[3] = __uint_as_float(su.y & 0xffff0000u);
    s8[4] = __uint_as_float(su.z << 16); s8[5] = __uint_as_float(su.z & 0xffff0000u);
    s8[6] = __uint_as_float(su.w << 16); s8[7] = __uint_as_float(su.w & 0xffff0000u);
    float4 bl = ((const float4*)b)[2 * v];
    float4 bhv = ((const float4*)b)[2 * v + 1];
    float bb[8] = {bl.x, bl.y, bl.z, bl.w, bhv.x, bhv.y, bhv.z, bhv.w};
    float e = 1.0f + eps_p[0];
    ushort_t r[8];
#pragma unroll
    for (int k = 0; k < 8; ++k) {
        float vv = fmaf(e, s8[k], a0[k] + a1[k] + a2[k] + a3[k]) + bb[k];
        r[k] = f2bf(fmaxf(vv, 0.0f));
    }
    uint4 o;
    o.x = (uint_t)r[0] | ((uint_t)r[1] << 16);
    o.y = (uint_t)r[2] | ((uint_t)r[3] << 16);
    o.z = (uint_t)r[4] | ((uint_t)r[5] << 16);
    o.w = (uint_t)r[6] | ((uint_t)r[7] << 16);
    ((uint4*)out)[idx] = o;
}

// ================= fused GEMM2+3: h = relu(t1@W1b+b1b) [LDS] ; y2 = h@W2a ==================
// per wave: 16-row tile; h kept in padded LDS (stride 104 shorts) for A-re-fragmenting.

#define HSTRIDE 104   // 96 + 8 pad shorts; 52 words % 32 = 20 -> 2-way (free)

__global__ void k_mfma23(const ushort_t* __restrict__ t1, const ushort_t* __restrict__ wf,
                         const float* __restrict__ b1b, ushort_t* __restrict__ y2) {
    constexpr int KC = 3, NT1 = 6, NT2 = 2;
    __shared__ __align__(16) ushort_t hT[4][16 * HSTRIDE];
    int lane = threadIdx.x & 63;
    int widx = threadIdx.x >> 6;
    int tile = blockIdx.x * 4 + widx;
    bool live = tile < MT1;
    int row0 = tile * 16;
    int q = lane >> 4;
    int l16 = lane & 15;
    const short8* bfp1 = (const short8*)wf;          // W1b frags
    const short8* bfp2 = (const short8*)(wf + 9216); // W2a frags

    if (live) {
        short8 bf[NT1][KC];
#pragma unroll
        for (int nt = 0; nt < NT1; ++nt)
#pragma unroll
            for (int c = 0; c < KC; ++c)
                bf[nt][c] = bfp1[(nt * KC + c) * 64 + lane];

        short8 af[KC];
#pragma unroll
        for (int c = 0; c < KC; ++c) {
            uint4 av = *(const uint4*)(t1 + (size_t)(row0 + l16) * DD + c * 32 + q * 8);
            af[c] = *(short8*)&av;
        }

        f32x4 acc[NT1];
#pragma unroll
        for (int nt = 0; nt < NT1; ++nt) acc[nt] = (f32x4){0.f, 0.f, 0.f, 0.f};
#pragma unroll
        for (int nt = 0; nt < NT1; ++nt)
#pragma unroll
            for (int c = 0; c < KC; ++c)
                acc[nt] = __builtin_amdgcn_mfma_f32_16x16x32_bf16(af[c], bf[nt][c], acc[nt], 0, 0, 0);

        // epilogue 1 -> LDS (h tile, bf16)
#pragma unroll
        for (int nt = 0; nt < NT1; ++nt) {
            int col = nt * 16 + l16;
            float bv = b1b[col];
#pragma unroll
            for (int r = 0; r < 4; ++r)
                hT[widx][(q * 4 + r) * HSTRIDE + col] = f2bf(fmaxf(acc[nt][r] + bv, 0.0f));
        }
    }
    __syncthreads();
    if (!live) return;

    // A-frags of h from LDS
    short8 af2[KC];
#pragma unroll
    for (int c = 0; c < KC; ++c) {
        uint4 av = *(const uint4*)&hT[widx][l16 * HSTRIDE + c * 32 + q * 8];
        af2[c] = *(short8*)&av;
    }
    short8 bf2[NT2][KC];
#pragma unroll
    for (int nt = 0; nt < NT2; ++nt)
#pragma unroll
        for (int c = 0; c < KC; ++c)
            bf2[nt][c] = bfp2[(nt * KC + c) * 64 + lane];

    f32x4 acc2[NT2];
#pragma unroll
    for (int nt = 0; nt < NT2; ++nt) acc2[nt] = (f32x4){0.f, 0.f, 0.f, 0.f};
#pragma unroll
    for (int nt = 0; nt < NT2; ++nt)
#pragma unroll
        for (int c = 0; c < KC; ++c)
            acc2[nt] = __builtin_amdgcn_mfma_f32_16x16x32_bf16(af2[c], bf2[nt][c], acc2[nt], 0, 0, 0);

#pragma unroll
    for (int nt = 0; nt < NT2; ++nt) {
        int col = nt * 16 + l16;
#pragma unroll
        for (int r = 0; r < 4; ++r)
            y2[(size_t)(row0 + q * 4 + r) * HH + col] = f2bf(acc2[nt][r]);
    }
}

// ================= fused agg2 + tail ==========================================
// block = 64 rows x 4 threads. t2 = relu((1+e)y2 + agg(y2) + b2a) in fp32 LDS,
// then u = relu(t2@W2b+b2b) (8 cols/thread), out = u@Wh + bh (quad shuffle-reduce).

#define TSTRIDE 36   // 32 + 4 pad floats

__global__ void k_aggtail(const ushort_t* __restrict__ y2, const int* __restrict__ deg,
                          const ushort_t* __restrict__ ell, const float* __restrict__ eps_p,
                          const float* __restrict__ b2a, const float* __restrict__ W2b,
                          const float* __restrict__ b2b, const float* __restrict__ Wh,
                          const float* __restrict__ bhp, float* __restrict__ out) {
    __shared__ float t2f[64 * TSTRIDE];
    int row = threadIdx.x >> 2;
    int jg = threadIdx.x & 3;
    int i = blockIdx.x * 64 + row;
    bool live = i < NN;

    if (live) {
        const uint4* y4 = (const uint4*)y2;
        const ushort_t* er = ell + (size_t)i * ELLW;
        int d = min(deg[i], ELLW);
        float a0[8] = {0,0,0,0,0,0,0,0}, a1[8] = {0,0,0,0,0,0,0,0};
        float a2[8] = {0,0,0,0,0,0,0,0}, a3[8] = {0,0,0,0,0,0,0,0};
        int p = 0;
        for (; p + 4 <= d; p += 4) {
            int s0 = er[p], s1 = er[p+1], s2 = er[p+2], s3 = er[p+3];
            uint4 f0 = y4[(size_t)s0 * 4 + jg];
            uint4 f1 = y4[(size_t)s1 * 4 + jg];
            uint4 f2 = y4[(size_t)s2 * 4 + jg];
            uint4 f3 = y4[(size_t)s3 * 4 + jg];
            addbf8(a0, f0); addbf8(a1, f1); addbf8(a2, f2); addbf8(a3, f3);
        }
        for (; p < d; ++p) addbf8(a0, y4[(size_t)er[p] * 4 + jg]);

        uint4 su = y4[(size_t)i * 4 + jg];
        float s8[8];
        s8[0] = __uint_as_float(su.x << 16); s8[1] = __uint_as_float(su.x & 0xffff0000u);
        s8[2] = __uint_as_float(su.y << 16); s8[3] = __uint_as_float(su.y & 0xffff0000u);
        s8[4] = __uint_as_float(su.z << 16); s8[5] = __uint_as_float(su.z & 0xffff0000u);
        s8[6] = __uint_as_float(su.w << 16); s8[7] = __uint_as_float(su.w & 0xffff0000u);
        float4 bl = ((const float4*)b2a)[2 * jg];
        float4 bhv = ((const float4*)b2a)[2 * jg + 1];
        float bb[8] = {bl.x, bl.y, bl.z, bl.w, bhv.x, bhv.y, bhv.z, bhv.w};
        float e = 1.0f + eps_p[0];
#pragma unroll
        for (int k = 0; k < 8; ++k) {
            float vv = fmaf(e, s8[k], a0[k] + a1[k] + a2[k] + a3[k]) + bb[k];
            t2f[row * TSTRIDE + jg * 8 + k] = fmaxf(vv, 0.0f);
        }
    }
    __syncthreads();

    float o[OO] = {0.f, 0.f, 0.f, 0.f};
    if (live) {
        const float* tr = &t2f[row * TSTRIDE];
#pragma unroll
        for (int jj = 0; jj < 8; ++jj) {
            int j = jg * 8 + jj;
            float acc = b2b[j];
#pragma unroll 8
            for (int k = 0; k < HH; ++k)
                acc = fmaf(tr[k], W2b[k * HH + j], acc);
            acc = fmaxf(acc, 0.0f);
#pragma unroll
            for (int oo = 0; oo < OO; ++oo)
                o[oo] = fmaf(acc, Wh[j * OO + oo], o[oo]);
        }
    }
#pragma unroll
    for (int oo = 0; oo < OO; ++oo) {
        o[oo] += __shfl_xor(o[oo], 1);
        o[oo] += __shfl_xor(o[oo], 2);
    }
    if (live && jg == 0) {
        float4 ov = {o[0] + bhp[0], o[1] + bhp[1], o[2] + bhp[2], o[3] + bhp[3]};
        ((float4*)out)[i] = ov;
    }
}

// ================= launch =================

extern "C" void kernel_launch(void* const* d_in, const int* in_sizes, int n_in,
                              void* d_out, int out_size, void* d_ws, size_t ws_size,
                              hipStream_t stream) {
    const float* x    = (const float*)d_in[0];
    const int*   edges= (const int*)d_in[1];
    const float* eps1 = (const float*)d_in[2];
    const float* eps2 = (const float*)d_in[3];
    const float* W1a  = (const float*)d_in[4];
    const float* b1a  = (const float*)d_in[5];
    const float* W1b  = (const float*)d_in[6];
    const float* b1b  = (const float*)d_in[7];
    const float* W2a  = (const float*)d_in[8];
    const float* b2a  = (const float*)d_in[9];
    const float* W2b  = (const float*)d_in[10];
    const float* b2b  = (const float*)d_in[11];
    const float* Wh   = (const float*)d_in[12];
    const float* bh   = (const float*)d_in[13];

    auto al = [](size_t n) { return (n + 255) / 256 * 256; };
    char* w = (char*)d_ws;
    int*      cur   = (int*)w;       w += al((size_t)NN * 4);          // degree after build
    ushort_t* ell   = (ushort_t*)w;  w += al((size_t)NN * ELLW * 2);   // 6.4 MB
    ushort_t* wf    = (ushort_t*)w;  w += al((size_t)(9216 + 3072) * 2); // W1b_f | W2a_f
    ushort_t* y1    = (ushort_t*)w;  w += al((size_t)NN * DD * 2);
    ushort_t* t1    = (ushort_t*)w;  w += al((size_t)NN * DD * 2);
    ushort_t* y2    = (ushort_t*)w;  w += al((size_t)NN * HH * 2);

    const int B = 256;

    hipMemsetAsync(cur, 0, (size_t)NN * 4, stream);
    k_big1<<<EDGE_B + WF_B + MFMA1_B, B, 0, stream>>>(edges, cur, ell, W1b, W2a, wf,
                                                      x, W1a, y1);
    k_aggb<DD><<<(NN * (DD/8) + B - 1) / B, B, 0, stream>>>(y1, cur, ell, eps1, b1a, t1);
    k_mfma23<<<MFMA1_B, B, 0, stream>>>(t1, wf, b1b, y2);
    k_aggtail<<<(NN + 63) / 64, B, 0, stream>>>(y2, cur, ell, eps2, b2a, W2b, b2b, Wh, bh,
                                                (float*)d_out);
}

// Round 9
// 206.824 us; speedup vs baseline: 4.5174x; 1.0721x over previous
//
#include <hip/hip_runtime.h>

#define NN 50000
#define NE 800000
#define DD 96
#define HH 32
#define OO 4
#define ELLW 64            // max degree; deg ~ Poisson(16), guarded/clamped
#define NBUCK ((NN + 255) / 256)   // 196 buckets of 256 nodes
#define BCAP 8192          // per-bucket edge capacity (mean 4081, sd 64 -> 64 sd)

typedef unsigned short ushort_t;
typedef unsigned int uint_t;
typedef __attribute__((ext_vector_type(8))) short short8;
typedef __attribute__((ext_vector_type(4))) float f32x4;

__device__ inline ushort_t f2bf(float f) {
    uint_t b = __float_as_uint(f);
    return (ushort_t)((b + 0x7fffu + ((b >> 16) & 1u)) >> 16);   // RNE
}

__device__ inline void addbf8(float* a, uint4 u) {
    a[0] += __uint_as_float(u.x << 16);
    a[1] += __uint_as_float(u.x & 0xffff0000u);
    a[2] += __uint_as_float(u.y << 16);
    a[3] += __uint_as_float(u.y & 0xffff0000u);
    a[4] += __uint_as_float(u.z << 16);
    a[5] += __uint_as_float(u.z & 0xffff0000u);
    a[6] += __uint_as_float(u.w << 16);
    a[7] += __uint_as_float(u.w & 0xffff0000u);
}

// ================= k1: edge bucketing (A) | W1b/W2a frag swizzle | y1 = x @ W1a ============

#define BA_B   ((NE / 4 + 255) / 256)        // 782
#define WF_B   6                              // 1152 (W1b) + 384 (W2a) frag-threads
#define MT1    (NN / 16)                      // 3125 M tiles
#define MFMA1_B ((MT1 + 3) / 4)               // 782

__global__ void k_big1(const int* __restrict__ edges, int* __restrict__ bcnt,
                       uint_t* __restrict__ packed,
                       const float* __restrict__ W1b, const float* __restrict__ W2a,
                       ushort_t* __restrict__ wf,
                       const float* __restrict__ x, const float* __restrict__ W1a,
                       ushort_t* __restrict__ y1) {
    int b = blockIdx.x;
    if (b < BA_B) {
        // ---- bucket phase A: 4 edges/thread, LDS hist + one global atomic/bucket/block ----
        __shared__ int hist[256];
        __shared__ int basesh[256];
        int thr = threadIdx.x;
        int t4 = b * 256 + thr;
        bool live = t4 < NE / 4;
        int4 ss = {0,0,0,0}, tt = {0,0,0,0};
        if (live) {
            ss = ((const int4*)edges)[t4];
            tt = ((const int4*)(edges + NE))[t4];
        }
        hist[thr] = 0;
        __syncthreads();
        if (live) {
            atomicAdd(&hist[tt.x >> 8], 1);
            atomicAdd(&hist[tt.y >> 8], 1);
            atomicAdd(&hist[tt.z >> 8], 1);
            atomicAdd(&hist[tt.w >> 8], 1);
        }
        __syncthreads();
        if (thr < NBUCK) {
            int c = hist[thr];
            basesh[thr] = c ? atomicAdd(&bcnt[thr], c) : 0;
        }
        __syncthreads();
        hist[thr] = 0;
        __syncthreads();
        if (live) {
            int d0 = tt.x, d1 = tt.y, d2 = tt.z, d3 = tt.w;
            int b0 = d0 >> 8, b1 = d1 >> 8, b2 = d2 >> 8, b3 = d3 >> 8;
            int p0 = basesh[b0] + atomicAdd(&hist[b0], 1);
            int p1 = basesh[b1] + atomicAdd(&hist[b1], 1);
            int p2 = basesh[b2] + atomicAdd(&hist[b2], 1);
            int p3 = basesh[b3] + atomicAdd(&hist[b3], 1);
            if (p0 < BCAP) packed[(size_t)b0 * BCAP + p0] = ((uint_t)ss.x << 8) | (d0 & 255);
            if (p1 < BCAP) packed[(size_t)b1 * BCAP + p1] = ((uint_t)ss.y << 8) | (d1 & 255);
            if (p2 < BCAP) packed[(size_t)b2 * BCAP + p2] = ((uint_t)ss.z << 8) | (d2 & 255);
            if (p3 < BCAP) packed[(size_t)b3 * BCAP + p3] = ((uint_t)ss.w << 8) | (d3 & 255);
        }
        return;
    }
    b -= BA_B;
    if (b < WF_B) {
        int tw = b * 256 + threadIdx.x;
        if (tw < 1152 + 384) {
            const float* Wsrc; ushort_t* dst; int KOUT, fl;
            if (tw < 1152) { Wsrc = W1b; dst = wf;        KOUT = DD; fl = tw; }
            else           { Wsrc = W2a; dst = wf + 9216; KOUT = HH; fl = tw - 1152; }
            int lane = fl & 63;
            int fc = fl >> 6;
            int c = fc % 3, nt = fc / 3;
            int kb = c * 32 + (lane >> 4) * 8;
            int col = nt * 16 + (lane & 15);
            ushort_t v[8];
#pragma unroll
            for (int j = 0; j < 8; ++j)
                v[j] = f2bf(Wsrc[(size_t)(kb + j) * KOUT + col]);
            *(uint4*)(dst + (size_t)fl * 8) = *(uint4*)v;
        }
        return;
    }
    b -= WF_B;
    // ---- mfma1: y1 = x @ W1a (raw fp32 A and B, inline cvt) ----
    constexpr int KC = 3, NT = 6;
    int lane = threadIdx.x & 63;
    int widx = threadIdx.x >> 6;
    int tile = b * 4 + widx;
    if (tile >= MT1) return;
    int row0 = tile * 16;
    int q = lane >> 4;
    int l16 = lane & 15;

    short8 bf[NT][KC];
#pragma unroll
    for (int nt = 0; nt < NT; ++nt)
#pragma unroll
        for (int c = 0; c < KC; ++c) {
            ushort_t v[8];
#pragma unroll
            for (int j = 0; j < 8; ++j)
                v[j] = f2bf(W1a[(size_t)(c * 32 + q * 8 + j) * DD + nt * 16 + l16]);
            bf[nt][c] = *(short8*)v;
        }

    short8 af[KC];
#pragma unroll
    for (int c = 0; c < KC; ++c) {
        const float* ap = x + (size_t)(row0 + l16) * DD + c * 32 + q * 8;
        float4 f0 = *(const float4*)ap;
        float4 f1 = *(const float4*)(ap + 4);
        ushort_t v[8] = {f2bf(f0.x), f2bf(f0.y), f2bf(f0.z), f2bf(f0.w),
                         f2bf(f1.x), f2bf(f1.y), f2bf(f1.z), f2bf(f1.w)};
        af[c] = *(short8*)v;
    }

    f32x4 acc[NT];
#pragma unroll
    for (int nt = 0; nt < NT; ++nt) acc[nt] = (f32x4){0.f, 0.f, 0.f, 0.f};
#pragma unroll
    for (int nt = 0; nt < NT; ++nt)
#pragma unroll
        for (int c = 0; c < KC; ++c)
            acc[nt] = __builtin_amdgcn_mfma_f32_16x16x32_bf16(af[c], bf[nt][c], acc[nt], 0, 0, 0);

#pragma unroll
    for (int nt = 0; nt < NT; ++nt) {
        int col = nt * 16 + l16;
#pragma unroll
        for (int r = 0; r < 4; ++r)
            y1[(size_t)(row0 + q * 4 + r) * DD + col] = f2bf(acc[nt][r]);
    }
}

// ================= phase B: per-bucket ELL fill via LDS counters =================

__global__ void k_bucketB(const int* __restrict__ bcnt, const uint_t* __restrict__ packed,
                          ushort_t* __restrict__ ell, int* __restrict__ deg) {
    __shared__ int curL[256];
    int b = blockIdx.x;
    int thr = threadIdx.x;
    int n0 = b * 256;
    curL[thr] = 0;
    __syncthreads();
    int cnt = min(bcnt[b], BCAP);
    const uint_t* pk = packed + (size_t)b * BCAP;
    for (int e = thr; e < cnt; e += 256) {
        uint_t u = pk[e];
        int doff = u & 255;
        int src = u >> 8;
        int p = atomicAdd(&curL[doff], 1);
        if (p < ELLW) ell[(size_t)(n0 + doff) * ELLW + p] = (ushort_t)src;
    }
    __syncthreads();
    if (n0 + thr < NN) deg[n0 + thr] = curL[thr];
}

// ================= aggregation over ELL (bf16): t1 = relu((1+e)y[i] + sum y[s] + b) =========

template <int DIM>
__global__ void k_aggb(const ushort_t* __restrict__ y, const int* __restrict__ deg,
                       const ushort_t* __restrict__ ell, const float* __restrict__ eps_p,
                       const float* __restrict__ b, ushort_t* __restrict__ out) {
    constexpr int V = DIM / 8;
    int idx = blockIdx.x * blockDim.x + threadIdx.x;
    if (idx >= NN * V) return;
    int i = idx / V, v = idx - i * V;
    const uint4* y4 = (const uint4*)y;
    const ushort_t* er = ell + (size_t)i * ELLW;
    int d = min(deg[i], ELLW);
    float a0[8] = {0,0,0,0,0,0,0,0}, a1[8] = {0,0,0,0,0,0,0,0};
    float a2[8] = {0,0,0,0,0,0,0,0}, a3[8] = {0,0,0,0,0,0,0,0};
    int p = 0;
    for (; p + 8 <= d; p += 8) {
        int s0 = er[p],   s1 = er[p+1], s2 = er[p+2], s3 = er[p+3];
        int s4 = er[p+4], s5 = er[p+5], s6 = er[p+6], s7 = er[p+7];
        uint4 f0 = y4[(size_t)s0 * V + v];
        uint4 f1 = y4[(size_t)s1 * V + v];
        uint4 f2 = y4[(size_t)s2 * V + v];
        uint4 f3 = y4[(size_t)s3 * V + v];
        uint4 f4 = y4[(size_t)s4 * V + v];
        uint4 f5 = y4[(size_t)s5 * V + v];
        uint4 f6 = y4[(size_t)s6 * V + v];
        uint4 f7 = y4[(size_t)s7 * V + v];
        addbf8(a0, f0); addbf8(a1, f1); addbf8(a2, f2); addbf8(a3, f3);
        addbf8(a0, f4); addbf8(a1, f5); addbf8(a2, f6); addbf8(a3, f7);
    }
    for (; p + 4 <= d; p += 4) {
        int s0 = er[p], s1 = er[p+1], s2 = er[p+2], s3 = er[p+3];
        uint4 f0 = y4[(size_t)s0 * V + v];
        uint4 f1 = y4[(size_t)s1 * V + v];
        uint4 f2 = y4[(size_t)s2 * V + v];
        uint4 f3 = y4[(size_t)s3 * V + v];
        addbf8(a0, f0); addbf8(a1, f1); addbf8(a2, f2); addbf8(a3, f3);
    }
    for (; p < d; ++p) addbf8(a0, y4[(size_t)er[p] * V + v]);

    uint4 su = y4[(size_t)i * V + v];
    float s8[8];
    s8[0] = __uint_as_float(su.x << 16); s8[1] = __uint_as_float(su.x & 0xffff0000u);
    s8[2] = __uint_as_float(su.y << 16); s8[3] = __uint_as_float(su.y & 0xffff0000u);
    s8[4] = __uint_as_float(su.z << 16); s8[5] = __uint_as_float(su.z & 0xffff0000u);
    s8[6] = __uint_as_float(su.w << 16); s8[7] = __uint_as_float(su.w & 0xffff0000u);
    float4 bl = ((const float4*)b)[2 * v];
    float4 bhv = ((const float4*)b)[2 * v + 1];
    float bb[8] = {bl.x, bl.y, bl.z, bl.w, bhv.x, bhv.y, bhv.z, bhv.w};
    float e = 1.0f + eps_p[0];
    ushort_t r[8];
#pragma unroll
    for (int k = 0; k < 8; ++k) {
        float vv = fmaf(e, s8[k], a0[k] + a1[k] + a2[k] + a3[k]) + bb[k];
        r[k] = f2bf(fmaxf(vv, 0.0f));
    }
    uint4 o;
    o.x = (uint_t)r[0] | ((uint_t)r[1] << 16);
    o.y = (uint_t)r[2] | ((uint_t)r[3] << 16);
    o.z = (uint_t)r[4] | ((uint_t)r[5] << 16);
    o.w = (uint_t)r[6] | ((uint_t)r[7] << 16);
    ((uint4*)out)[idx] = o;
}

// ================= fused GEMM2+3: h = relu(t1@W1b+b1b) [LDS] ; y2 = h@W2a ==================

#define HSTRIDE 104   // 96 + 8 pad shorts

__global__ void k_mfma23(const ushort_t* __restrict__ t1, const ushort_t* __restrict__ wf,
                         const float* __restrict__ b1b, ushort_t* __restrict__ y2) {
    constexpr int KC = 3, NT1 = 6, NT2 = 2;
    __shared__ __align__(16) ushort_t hT[4][16 * HSTRIDE];
    int lane = threadIdx.x & 63;
    int widx = threadIdx.x >> 6;
    int tile = blockIdx.x * 4 + widx;
    bool live = tile < MT1;
    int row0 = tile * 16;
    int q = lane >> 4;
    int l16 = lane & 15;
    const short8* bfp1 = (const short8*)wf;
    const short8* bfp2 = (const short8*)(wf + 9216);

    if (live) {
        short8 bf[NT1][KC];
#pragma unroll
        for (int nt = 0; nt < NT1; ++nt)
#pragma unroll
            for (int c = 0; c < KC; ++c)
                bf[nt][c] = bfp1[(nt * KC + c) * 64 + lane];

        short8 af[KC];
#pragma unroll
        for (int c = 0; c < KC; ++c) {
            uint4 av = *(const uint4*)(t1 + (size_t)(row0 + l16) * DD + c * 32 + q * 8);
            af[c] = *(short8*)&av;
        }

        f32x4 acc[NT1];
#pragma unroll
        for (int nt = 0; nt < NT1; ++nt) acc[nt] = (f32x4){0.f, 0.f, 0.f, 0.f};
#pragma unroll
        for (int nt = 0; nt < NT1; ++nt)
#pragma unroll
            for (int c = 0; c < KC; ++c)
                acc[nt] = __builtin_amdgcn_mfma_f32_16x16x32_bf16(af[c], bf[nt][c], acc[nt], 0, 0, 0);

#pragma unroll
        for (int nt = 0; nt < NT1; ++nt) {
            int col = nt * 16 + l16;
            float bv = b1b[col];
#pragma unroll
            for (int r = 0; r < 4; ++r)
                hT[widx][(q * 4 + r) * HSTRIDE + col] = f2bf(fmaxf(acc[nt][r] + bv, 0.0f));
        }
    }
    __syncthreads();
    if (!live) return;

    short8 af2[KC];
#pragma unroll
    for (int c = 0; c < KC; ++c) {
        uint4 av = *(const uint4*)&hT[widx][l16 * HSTRIDE + c * 32 + q * 8];
        af2[c] = *(short8*)&av;
    }
    short8 bf2[NT2][KC];
#pragma unroll
    for (int nt = 0; nt < NT2; ++nt)
#pragma unroll
        for (int c = 0; c < KC; ++c)
            bf2[nt][c] = bfp2[(nt * KC + c) * 64 + lane];

    f32x4 acc2[NT2];
#pragma unroll
    for (int nt = 0; nt < NT2; ++nt) acc2[nt] = (f32x4){0.f, 0.f, 0.f, 0.f};
#pragma unroll
    for (int nt = 0; nt < NT2; ++nt)
#pragma unroll
        for (int c = 0; c < KC; ++c)
            acc2[nt] = __builtin_amdgcn_mfma_f32_16x16x32_bf16(af2[c], bf2[nt][c], acc2[nt], 0, 0, 0);

#pragma unroll
    for (int nt = 0; nt < NT2; ++nt) {
        int col = nt * 16 + l16;
#pragma unroll
        for (int r = 0; r < 4; ++r)
            y2[(size_t)(row0 + q * 4 + r) * HH + col] = f2bf(acc2[nt][r]);
    }
}

// ================= fused agg2 + tail ==========================================

#define TSTRIDE 36   // 32 + 4 pad floats

__global__ void k_aggtail(const ushort_t* __restrict__ y2, const int* __restrict__ deg,
                          const ushort_t* __restrict__ ell, const float* __restrict__ eps_p,
                          const float* __restrict__ b2a, const float* __restrict__ W2b,
                          const float* __restrict__ b2b, const float* __restrict__ Wh,
                          const float* __restrict__ bhp, float* __restrict__ out) {
    __shared__ float t2f[64 * TSTRIDE];
    int row = threadIdx.x >> 2;
    int jg = threadIdx.x & 3;
    int i = blockIdx.x * 64 + row;
    bool live = i < NN;

    if (live) {
        const uint4* y4 = (const uint4*)y2;
        const ushort_t* er = ell + (size_t)i * ELLW;
        int d = min(deg[i], ELLW);
        float a0[8] = {0,0,0,0,0,0,0,0}, a1[8] = {0,0,0,0,0,0,0,0};
        float a2[8] = {0,0,0,0,0,0,0,0}, a3[8] = {0,0,0,0,0,0,0,0};
        int p = 0;
        for (; p + 4 <= d; p += 4) {
            int s0 = er[p], s1 = er[p+1], s2 = er[p+2], s3 = er[p+3];
            uint4 f0 = y4[(size_t)s0 * 4 + jg];
            uint4 f1 = y4[(size_t)s1 * 4 + jg];
            uint4 f2 = y4[(size_t)s2 * 4 + jg];
            uint4 f3 = y4[(size_t)s3 * 4 + jg];
            addbf8(a0, f0); addbf8(a1, f1); addbf8(a2, f2); addbf8(a3, f3);
        }
        for (; p < d; ++p) addbf8(a0, y4[(size_t)er[p] * 4 + jg]);

        uint4 su = y4[(size_t)i * 4 + jg];
        float s8[8];
        s8[0] = __uint_as_float(su.x << 16); s8[1] = __uint_as_float(su.x & 0xffff0000u);
        s8[2] = __uint_as_float(su.y << 16); s8[3] = __uint_as_float(su.y & 0xffff0000u);
        s8[4] = __uint_as_float(su.z << 16); s8[5] = __uint_as_float(su.z & 0xffff0000u);
        s8[6] = __uint_as_float(su.w << 16); s8[7] = __uint_as_float(su.w & 0xffff0000u);
        float4 bl = ((const float4*)b2a)[2 * jg];
        float4 bhv = ((const float4*)b2a)[2 * jg + 1];
        float bb[8] = {bl.x, bl.y, bl.z, bl.w, bhv.x, bhv.y, bhv.z, bhv.w};
        float e = 1.0f + eps_p[0];
#pragma unroll
        for (int k = 0; k < 8; ++k) {
            float vv = fmaf(e, s8[k], a0[k] + a1[k] + a2[k] + a3[k]) + bb[k];
            t2f[row * TSTRIDE + jg * 8 + k] = fmaxf(vv, 0.0f);
        }
    }
    __syncthreads();

    float o[OO] = {0.f, 0.f, 0.f, 0.f};
    if (live) {
        const float* tr = &t2f[row * TSTRIDE];
#pragma unroll
        for (int jj = 0; jj < 8; ++jj) {
            int j = jg * 8 + jj;
            float acc = b2b[j];
#pragma unroll 8
            for (int k = 0; k < HH; ++k)
                acc = fmaf(tr[k], W2b[k * HH + j], acc);
            acc = fmaxf(acc, 0.0f);
#pragma unroll
            for (int oo = 0; oo < OO; ++oo)
                o[oo] = fmaf(acc, Wh[j * OO + oo], o[oo]);
        }
    }
#pragma unroll
    for (int oo = 0; oo < OO; ++oo) {
        o[oo] += __shfl_xor(o[oo], 1);
        o[oo] += __shfl_xor(o[oo], 2);
    }
    if (live && jg == 0) {
        float4 ov = {o[0] + bhp[0], o[1] + bhp[1], o[2] + bhp[2], o[3] + bhp[3]};
        ((float4*)out)[i] = ov;
    }
}

// ================= launch =================

extern "C" void kernel_launch(void* const* d_in, const int* in_sizes, int n_in,
                              void* d_out, int out_size, void* d_ws, size_t ws_size,
                              hipStream_t stream) {
    const float* x    = (const float*)d_in[0];
    const int*   edges= (const int*)d_in[1];
    const float* eps1 = (const float*)d_in[2];
    const float* eps2 = (const float*)d_in[3];
    const float* W1a  = (const float*)d_in[4];
    const float* b1a  = (const float*)d_in[5];
    const float* W1b  = (const float*)d_in[6];
    const float* b1b  = (const float*)d_in[7];
    const float* W2a  = (const float*)d_in[8];
    const float* b2a  = (const float*)d_in[9];
    const float* W2b  = (const float*)d_in[10];
    const float* b2b  = (const float*)d_in[11];
    const float* Wh   = (const float*)d_in[12];
    const float* bh   = (const float*)d_in[13];

    auto al = [](size_t n) { return (n + 255) / 256 * 256; };
    char* w = (char*)d_ws;
    int*      bcnt   = (int*)w;      w += al((size_t)NBUCK * 4);
    uint_t*   packed = (uint_t*)w;   w += al((size_t)NBUCK * BCAP * 4);    // 6.4 MB
    int*      deg    = (int*)w;      w += al((size_t)NN * 4);
    ushort_t* ell    = (ushort_t*)w; w += al((size_t)NN * ELLW * 2);       // 6.4 MB
    ushort_t* wf     = (ushort_t*)w; w += al((size_t)(9216 + 3072) * 2);
    ushort_t* y1     = (ushort_t*)w; w += al((size_t)NN * DD * 2);
    ushort_t* t1     = (ushort_t*)w; w += al((size_t)NN * DD * 2);
    ushort_t* y2     = (ushort_t*)w; w += al((size_t)NN * HH * 2);

    const int B = 256;

    hipMemsetAsync(bcnt, 0, (size_t)NBUCK * 4, stream);
    k_big1<<<BA_B + WF_B + MFMA1_B, B, 0, stream>>>(edges, bcnt, packed, W1b, W2a, wf,
                                                    x, W1a, y1);
    k_bucketB<<<NBUCK, B, 0, stream>>>(bcnt, packed, ell, deg);
    k_aggb<DD><<<(NN * (DD/8) + B - 1) / B, B, 0, stream>>>(y1, deg, ell, eps1, b1a, t1);
    k_mfma23<<<MFMA1_B, B, 0, stream>>>(t1, wf, b1b, y2);
    k_aggtail<<<(NN + 63) / 64, B, 0, stream>>>(y2, deg, ell, eps2, b2a, W2b, b2b, Wh, bh,
                                                (float*)d_out);
}

// Round 10
// 196.692 us; speedup vs baseline: 4.7501x; 1.0515x over previous
//
#include <hip/hip_runtime.h>

#define NN 50000
#define NE 800000
#define DD 96
#define HH 32
#define OO 4
#define ELLW 64            // max degree; deg ~ Poisson(16), guarded/clamped
#define NBUCK ((NN + 255) / 256)   // 196 buckets of 256 nodes
#define BCAP 8192          // per-bucket edge capacity

typedef unsigned short ushort_t;
typedef unsigned int uint_t;
typedef __attribute__((ext_vector_type(8))) short short8;
typedef __attribute__((ext_vector_type(4))) float f32x4;

__device__ inline ushort_t f2bf(float f) {
    uint_t b = __float_as_uint(f);
    return (ushort_t)((b + 0x7fffu + ((b >> 16) & 1u)) >> 16);   // RNE
}

__device__ inline void addbf8(float* a, uint4 u) {
    a[0] += __uint_as_float(u.x << 16);
    a[1] += __uint_as_float(u.x & 0xffff0000u);
    a[2] += __uint_as_float(u.y << 16);
    a[3] += __uint_as_float(u.y & 0xffff0000u);
    a[4] += __uint_as_float(u.z << 16);
    a[5] += __uint_as_float(u.z & 0xffff0000u);
    a[6] += __uint_as_float(u.w << 16);
    a[7] += __uint_as_float(u.w & 0xffff0000u);
}

// ================= k1: edge bucketing (A) | W1b/W2a frag swizzle | y1 = x @ W1a ============

#define BA_B   ((NE / 4 + 255) / 256)        // 782
#define WF_B   6                              // 1152 (W1b) + 384 (W2a) frag-threads
#define MT1    (NN / 16)                      // 3125 M tiles
#define MFMA1_B ((MT1 + 3) / 4)               // 782

__global__ void k_big1(const int* __restrict__ edges, int* __restrict__ bcnt,
                       uint_t* __restrict__ packed,
                       const float* __restrict__ W1b, const float* __restrict__ W2a,
                       ushort_t* __restrict__ wf,
                       const float* __restrict__ x, const float* __restrict__ W1a,
                       ushort_t* __restrict__ y1) {
    int b = blockIdx.x;
    if (b < BA_B) {
        __shared__ int hist[256];
        __shared__ int basesh[256];
        int thr = threadIdx.x;
        int t4 = b * 256 + thr;
        bool live = t4 < NE / 4;
        int4 ss = {0,0,0,0}, tt = {0,0,0,0};
        if (live) {
            ss = ((const int4*)edges)[t4];
            tt = ((const int4*)(edges + NE))[t4];
        }
        hist[thr] = 0;
        __syncthreads();
        if (live) {
            atomicAdd(&hist[tt.x >> 8], 1);
            atomicAdd(&hist[tt.y >> 8], 1);
            atomicAdd(&hist[tt.z >> 8], 1);
            atomicAdd(&hist[tt.w >> 8], 1);
        }
        __syncthreads();
        if (thr < NBUCK) {
            int c = hist[thr];
            basesh[thr] = c ? atomicAdd(&bcnt[thr], c) : 0;
        }
        __syncthreads();
        hist[thr] = 0;
        __syncthreads();
        if (live) {
            int d0 = tt.x, d1 = tt.y, d2 = tt.z, d3 = tt.w;
            int b0 = d0 >> 8, b1 = d1 >> 8, b2 = d2 >> 8, b3 = d3 >> 8;
            int p0 = basesh[b0] + atomicAdd(&hist[b0], 1);
            int p1 = basesh[b1] + atomicAdd(&hist[b1], 1);
            int p2 = basesh[b2] + atomicAdd(&hist[b2], 1);
            int p3 = basesh[b3] + atomicAdd(&hist[b3], 1);
            if (p0 < BCAP) packed[(size_t)b0 * BCAP + p0] = ((uint_t)ss.x << 8) | (d0 & 255);
            if (p1 < BCAP) packed[(size_t)b1 * BCAP + p1] = ((uint_t)ss.y << 8) | (d1 & 255);
            if (p2 < BCAP) packed[(size_t)b2 * BCAP + p2] = ((uint_t)ss.z << 8) | (d2 & 255);
            if (p3 < BCAP) packed[(size_t)b3 * BCAP + p3] = ((uint_t)ss.w << 8) | (d3 & 255);
        }
        return;
    }
    b -= BA_B;
    if (b < WF_B) {
        int tw = b * 256 + threadIdx.x;
        if (tw < 1152 + 384) {
            const float* Wsrc; ushort_t* dst; int KOUT, fl;
            if (tw < 1152) { Wsrc = W1b; dst = wf;        KOUT = DD; fl = tw; }
            else           { Wsrc = W2a; dst = wf + 9216; KOUT = HH; fl = tw - 1152; }
            int lane = fl & 63;
            int fc = fl >> 6;
            int c = fc % 3, nt = fc / 3;
            int kb = c * 32 + (lane >> 4) * 8;
            int col = nt * 16 + (lane & 15);
            ushort_t v[8];
#pragma unroll
            for (int j = 0; j < 8; ++j)
                v[j] = f2bf(Wsrc[(size_t)(kb + j) * KOUT + col]);
            *(uint4*)(dst + (size_t)fl * 8) = *(uint4*)v;
        }
        return;
    }
    b -= WF_B;
    constexpr int KC = 3, NT = 6;
    int lane = threadIdx.x & 63;
    int widx = threadIdx.x >> 6;
    int tile = b * 4 + widx;
    if (tile >= MT1) return;
    int row0 = tile * 16;
    int q = lane >> 4;
    int l16 = lane & 15;

    short8 bf[NT][KC];
#pragma unroll
    for (int nt = 0; nt < NT; ++nt)
#pragma unroll
        for (int c = 0; c < KC; ++c) {
            ushort_t v[8];
#pragma unroll
            for (int j = 0; j < 8; ++j)
                v[j] = f2bf(W1a[(size_t)(c * 32 + q * 8 + j) * DD + nt * 16 + l16]);
            bf[nt][c] = *(short8*)v;
        }

    short8 af[KC];
#pragma unroll
    for (int c = 0; c < KC; ++c) {
        const float* ap = x + (size_t)(row0 + l16) * DD + c * 32 + q * 8;
        float4 f0 = *(const float4*)ap;
        float4 f1 = *(const float4*)(ap + 4);
        ushort_t v[8] = {f2bf(f0.x), f2bf(f0.y), f2bf(f0.z), f2bf(f0.w),
                         f2bf(f1.x), f2bf(f1.y), f2bf(f1.z), f2bf(f1.w)};
        af[c] = *(short8*)v;
    }

    f32x4 acc[NT];
#pragma unroll
    for (int nt = 0; nt < NT; ++nt) acc[nt] = (f32x4){0.f, 0.f, 0.f, 0.f};
#pragma unroll
    for (int nt = 0; nt < NT; ++nt)
#pragma unroll
        for (int c = 0; c < KC; ++c)
            acc[nt] = __builtin_amdgcn_mfma_f32_16x16x32_bf16(af[c], bf[nt][c], acc[nt], 0, 0, 0);

#pragma unroll
    for (int nt = 0; nt < NT; ++nt) {
        int col = nt * 16 + l16;
#pragma unroll
        for (int r = 0; r < 4; ++r)
            y1[(size_t)(row0 + q * 4 + r) * DD + col] = f2bf(acc[nt][r]);
    }
}

// ================= phase B: per-bucket ELL fill via LDS counters =================

__global__ void k_bucketB(const int* __restrict__ bcnt, const uint_t* __restrict__ packed,
                          ushort_t* __restrict__ ell, int* __restrict__ deg) {
    __shared__ int curL[256];
    int b = blockIdx.x;
    int thr = threadIdx.x;
    int n0 = b * 256;
    curL[thr] = 0;
    __syncthreads();
    int cnt = min(bcnt[b], BCAP);
    const uint_t* pk = packed + (size_t)b * BCAP;
    for (int e = thr; e < cnt; e += 256) {
        uint_t u = pk[e];
        int doff = u & 255;
        int src = u >> 8;
        int p = atomicAdd(&curL[doff], 1);
        if (p < ELLW) ell[(size_t)(n0 + doff) * ELLW + p] = (ushort_t)src;
    }
    __syncthreads();
    if (n0 + thr < NN) deg[n0 + thr] = curL[thr];
}

// ================= agg layer 1: t1 = relu((1+e)y[i] + sum y[s] + b), 2-way edge split =======
// thread layout: idx = row*24 + v*2 + part; partner lanes adjacent (xor 1).

__global__ void k_aggb96(const ushort_t* __restrict__ y, const int* __restrict__ deg,
                         const ushort_t* __restrict__ ell, const float* __restrict__ eps_p,
                         const float* __restrict__ b, ushort_t* __restrict__ out) {
    constexpr int V = DD / 8;   // 12 slices
    int idx = blockIdx.x * blockDim.x + threadIdx.x;
    if (idx >= NN * V * 2) return;
    int i = idx / (V * 2);
    int rem = idx - i * (V * 2);
    int v = rem >> 1, part = rem & 1;
    const uint4* y4 = (const uint4*)y;
    const ushort_t* er = ell + (size_t)i * ELLW;
    int d = min(deg[i], ELLW);
    float a0[8] = {0,0,0,0,0,0,0,0}, a1[8] = {0,0,0,0,0,0,0,0};
    float a2[8] = {0,0,0,0,0,0,0,0}, a3[8] = {0,0,0,0,0,0,0,0};
    int p = part;
    for (; p + 6 < d; p += 8) {
        int s0 = er[p], s1 = er[p+2], s2 = er[p+4], s3 = er[p+6];
        uint4 f0 = y4[(size_t)s0 * V + v];
        uint4 f1 = y4[(size_t)s1 * V + v];
        uint4 f2 = y4[(size_t)s2 * V + v];
        uint4 f3 = y4[(size_t)s3 * V + v];
        addbf8(a0, f0); addbf8(a1, f1); addbf8(a2, f2); addbf8(a3, f3);
    }
    for (; p < d; p += 2) addbf8(a0, y4[(size_t)er[p] * V + v]);

    float s[8];
#pragma unroll
    for (int k = 0; k < 8; ++k) {
        s[k] = a0[k] + a1[k] + a2[k] + a3[k];
        s[k] += __shfl_xor(s[k], 1);          // combine parts (adjacent lanes)
    }
    if (part) return;

    uint4 su = y4[(size_t)i * V + v];
    float s8[8];
    s8[0] = __uint_as_float(su.x << 16); s8[1] = __uint_as_float(su.x & 0xffff0000u);
    s8[2] = __uint_as_float(su.y << 16); s8[3] = __uint_as_float(su.y & 0xffff0000u);
    s8[4] = __uint_as_float(su.z << 16); s8[5] = __uint_as_float(su.z & 0xffff0000u);
    s8[6] = __uint_as_float(su.w << 16); s8[7] = __uint_as_float(su.w & 0xffff0000u);
    float4 bl = ((const float4*)b)[2 * v];
    float4 bhv = ((const float4*)b)[2 * v + 1];
    float bb[8] = {bl.x, bl.y, bl.z, bl.w, bhv.x, bhv.y, bhv.z, bhv.w};
    float e = 1.0f + eps_p[0];
    ushort_t r[8];
#pragma unroll
    for (int k = 0; k < 8; ++k) {
        float vv = fmaf(e, s8[k], s[k]) + bb[k];
        r[k] = f2bf(fmaxf(vv, 0.0f));
    }
    uint4 o;
    o.x = (uint_t)r[0] | ((uint_t)r[1] << 16);
    o.y = (uint_t)r[2] | ((uint_t)r[3] << 16);
    o.z = (uint_t)r[4] | ((uint_t)r[5] << 16);
    o.w = (uint_t)r[6] | ((uint_t)r[7] << 16);
    ((uint4*)out)[(size_t)i * V + v] = o;
}

// ================= fused GEMM2+3: h = relu(t1@W1b+b1b) [LDS] ; y2 = h@W2a ==================

#define HSTRIDE 104   // 96 + 8 pad shorts

__global__ void k_mfma23(const ushort_t* __restrict__ t1, const ushort_t* __restrict__ wf,
                         const float* __restrict__ b1b, ushort_t* __restrict__ y2) {
    constexpr int KC = 3, NT1 = 6, NT2 = 2;
    __shared__ __align__(16) ushort_t hT[4][16 * HSTRIDE];
    int lane = threadIdx.x & 63;
    int widx = threadIdx.x >> 6;
    int tile = blockIdx.x * 4 + widx;
    bool live = tile < MT1;
    int row0 = tile * 16;
    int q = lane >> 4;
    int l16 = lane & 15;
    const short8* bfp1 = (const short8*)wf;
    const short8* bfp2 = (const short8*)(wf + 9216);

    if (live) {
        short8 bf[NT1][KC];
#pragma unroll
        for (int nt = 0; nt < NT1; ++nt)
#pragma unroll
            for (int c = 0; c < KC; ++c)
                bf[nt][c] = bfp1[(nt * KC + c) * 64 + lane];

        short8 af[KC];
#pragma unroll
        for (int c = 0; c < KC; ++c) {
            uint4 av = *(const uint4*)(t1 + (size_t)(row0 + l16) * DD + c * 32 + q * 8);
            af[c] = *(short8*)&av;
        }

        f32x4 acc[NT1];
#pragma unroll
        for (int nt = 0; nt < NT1; ++nt) acc[nt] = (f32x4){0.f, 0.f, 0.f, 0.f};
#pragma unroll
        for (int nt = 0; nt < NT1; ++nt)
#pragma unroll
            for (int c = 0; c < KC; ++c)
                acc[nt] = __builtin_amdgcn_mfma_f32_16x16x32_bf16(af[c], bf[nt][c], acc[nt], 0, 0, 0);

#pragma unroll
        for (int nt = 0; nt < NT1; ++nt) {
            int col = nt * 16 + l16;
            float bv = b1b[col];
#pragma unroll
            for (int r = 0; r < 4; ++r)
                hT[widx][(q * 4 + r) * HSTRIDE + col] = f2bf(fmaxf(acc[nt][r] + bv, 0.0f));
        }
    }
    __syncthreads();
    if (!live) return;

    short8 af2[KC];
#pragma unroll
    for (int c = 0; c < KC; ++c) {
        uint4 av = *(const uint4*)&hT[widx][l16 * HSTRIDE + c * 32 + q * 8];
        af2[c] = *(short8*)&av;
    }
    short8 bf2[NT2][KC];
#pragma unroll
    for (int nt = 0; nt < NT2; ++nt)
#pragma unroll
        for (int c = 0; c < KC; ++c)
            bf2[nt][c] = bfp2[(nt * KC + c) * 64 + lane];

    f32x4 acc2[NT2];
#pragma unroll
    for (int nt = 0; nt < NT2; ++nt) acc2[nt] = (f32x4){0.f, 0.f, 0.f, 0.f};
#pragma unroll
    for (int nt = 0; nt < NT2; ++nt)
#pragma unroll
        for (int c = 0; c < KC; ++c)
            acc2[nt] = __builtin_amdgcn_mfma_f32_16x16x32_bf16(af2[c], bf2[nt][c], acc2[nt], 0, 0, 0);

#pragma unroll
    for (int nt = 0; nt < NT2; ++nt) {
        int col = nt * 16 + l16;
#pragma unroll
        for (int r = 0; r < 4; ++r)
            y2[(size_t)(row0 + q * 4 + r) * HH + col] = f2bf(acc2[nt][r]);
    }
}

// ================= fused agg2 + tail: 16 rows x 16 threads (4 parts x 4 slices) =============

#define TSTRIDE 36   // 32 + 4 pad floats
#define ATR 16       // rows per block

__global__ void k_aggtail(const ushort_t* __restrict__ y2, const int* __restrict__ deg,
                          const ushort_t* __restrict__ ell, const float* __restrict__ eps_p,
                          const float* __restrict__ b2a, const float* __restrict__ W2b,
                          const float* __restrict__ b2b, const float* __restrict__ Wh,
                          const float* __restrict__ bhp, float* __restrict__ out) {
    __shared__ float t2f[ATR * TSTRIDE];
    int row = threadIdx.x >> 4;        // 0..15
    int sub = threadIdx.x & 15;
    int jg = sub & 3;                  // 16B slice
    int part = sub >> 2;               // edge partition (lane bits 2,3)
    int i = blockIdx.x * ATR + row;
    bool live = i < NN;

    if (live) {
        const uint4* y4 = (const uint4*)y2;
        const ushort_t* er = ell + (size_t)i * ELLW;
        int d = min(deg[i], ELLW);
        float a0[8] = {0,0,0,0,0,0,0,0}, a1[8] = {0,0,0,0,0,0,0,0};
        int p = part;
        for (; p + 4 < d; p += 8) {
            int s0 = er[p], s1 = er[p + 4];
            uint4 f0 = y4[(size_t)s0 * 4 + jg];
            uint4 f1 = y4[(size_t)s1 * 4 + jg];
            addbf8(a0, f0); addbf8(a1, f1);
        }
        for (; p < d; p += 4) addbf8(a0, y4[(size_t)er[p] * 4 + jg]);

        float s[8];
#pragma unroll
        for (int k = 0; k < 8; ++k) {
            s[k] = a0[k] + a1[k];
            s[k] += __shfl_xor(s[k], 4);
            s[k] += __shfl_xor(s[k], 8);
        }
        if (part == 0) {
            uint4 su = y4[(size_t)i * 4 + jg];
            float s8[8];
            s8[0] = __uint_as_float(su.x << 16); s8[1] = __uint_as_float(su.x & 0xffff0000u);
            s8[2] = __uint_as_float(su.y << 16); s8[3] = __uint_as_float(su.y & 0xffff0000u);
            s8[4] = __uint_as_float(su.z << 16); s8[5] = __uint_as_float(su.z & 0xffff0000u);
            s8[6] = __uint_as_float(su.w << 16); s8[7] = __uint_as_float(su.w & 0xffff0000u);
            float4 bl = ((const float4*)b2a)[2 * jg];
            float4 bhv = ((const float4*)b2a)[2 * jg + 1];
            float bb[8] = {bl.x, bl.y, bl.z, bl.w, bhv.x, bhv.y, bhv.z, bhv.w};
            float e = 1.0f + eps_p[0];
#pragma unroll
            for (int k = 0; k < 8; ++k) {
                float vv = fmaf(e, s8[k], s[k]) + bb[k];
                t2f[row * TSTRIDE + jg * 8 + k] = fmaxf(vv, 0.0f);
            }
        }
    }
    __syncthreads();

    float o[OO] = {0.f, 0.f, 0.f, 0.f};
    if (live) {
        const float* tr = &t2f[row * TSTRIDE];
#pragma unroll
        for (int jj = 0; jj < 2; ++jj) {
            int j = sub * 2 + jj;
            float acc = b2b[j];
#pragma unroll 8
            for (int k = 0; k < HH; ++k)
                acc = fmaf(tr[k], W2b[k * HH + j], acc);
            acc = fmaxf(acc, 0.0f);
#pragma unroll
            for (int oo = 0; oo < OO; ++oo)
                o[oo] = fmaf(acc, Wh[j * OO + oo], o[oo]);
        }
    }
#pragma unroll
    for (int oo = 0; oo < OO; ++oo) {
        o[oo] += __shfl_xor(o[oo], 1);
        o[oo] += __shfl_xor(o[oo], 2);
        o[oo] += __shfl_xor(o[oo], 4);
        o[oo] += __shfl_xor(o[oo], 8);
    }
    if (live && sub == 0) {
        float4 ov = {o[0] + bhp[0], o[1] + bhp[1], o[2] + bhp[2], o[3] + bhp[3]};
        ((float4*)out)[i] = ov;
    }
}

// ================= launch =================

extern "C" void kernel_launch(void* const* d_in, const int* in_sizes, int n_in,
                              void* d_out, int out_size, void* d_ws, size_t ws_size,
                              hipStream_t stream) {
    const float* x    = (const float*)d_in[0];
    const int*   edges= (const int*)d_in[1];
    const float* eps1 = (const float*)d_in[2];
    const float* eps2 = (const float*)d_in[3];
    const float* W1a  = (const float*)d_in[4];
    const float* b1a  = (const float*)d_in[5];
    const float* W1b  = (const float*)d_in[6];
    const float* b1b  = (const float*)d_in[7];
    const float* W2a  = (const float*)d_in[8];
    const float* b2a  = (const float*)d_in[9];
    const float* W2b  = (const float*)d_in[10];
    const float* b2b  = (const float*)d_in[11];
    const float* Wh   = (const float*)d_in[12];
    const float* bh   = (const float*)d_in[13];

    auto al = [](size_t n) { return (n + 255) / 256 * 256; };
    char* w = (char*)d_ws;
    int*      bcnt   = (int*)w;      w += al((size_t)NBUCK * 4);
    uint_t*   packed = (uint_t*)w;   w += al((size_t)NBUCK * BCAP * 4);
    int*      deg    = (int*)w;      w += al((size_t)NN * 4);
    ushort_t* ell    = (ushort_t*)w; w += al((size_t)NN * ELLW * 2);
    ushort_t* wf     = (ushort_t*)w; w += al((size_t)(9216 + 3072) * 2);
    ushort_t* y1     = (ushort_t*)w; w += al((size_t)NN * DD * 2);
    ushort_t* t1     = (ushort_t*)w; w += al((size_t)NN * DD * 2);
    ushort_t* y2     = (ushort_t*)w; w += al((size_t)NN * HH * 2);

    const int B = 256;

    hipMemsetAsync(bcnt, 0, (size_t)NBUCK * 4, stream);
    k_big1<<<BA_B + WF_B + MFMA1_B, B, 0, stream>>>(edges, bcnt, packed, W1b, W2a, wf,
                                                    x, W1a, y1);
    k_bucketB<<<NBUCK, B, 0, stream>>>(bcnt, packed, ell, deg);
    k_aggb96<<<(NN * (DD/8) * 2 + B - 1) / B, B, 0, stream>>>(y1, deg, ell, eps1, b1a, t1);
    k_mfma23<<<MFMA1_B, B, 0, stream>>>(t1, wf, b1b, y2);
    k_aggtail<<<(NN + ATR - 1) / ATR, B, 0, stream>>>(y2, deg, ell, eps2, b2a, W2b, b2b,
                                                      Wh, bh, (float*)d_out);
}